// Round 2
// baseline (8349.841 us; speedup 1.0000x reference)
//
#include <hip/hip_runtime.h>
#include <math.h>

typedef float f32;

#define TT 512
#define BB 64
#define DD 256
#define NN 48
#define CHT 128   // time chunk for px
#define CHB 16    // batch chunk for attention

// ===== workspace offsets (bytes). Peak ~134 MB =====
static const size_t OFF_HF  = 0;           // [512][64][256] f32
static const size_t OFF_HB  = 33554432;    // [512][64][256] f32
// px arena (phase 1), aliased by attention chunk buffers (phase 2):
static const size_t OFF_PXF = 67108864;    // [128][64][768] f32 (25.2 MB)
static const size_t OFF_PXB = 92274688;    // [128][64][768] f32 (25.2 MB)
static const size_t OFF_QC  = 67108864;    // [16][512][256] (8.4 MB)
static const size_t OFF_KC  = 75497472;    // [16][512][256]
static const size_t OFF_VC  = 83886080;    // [16][512][256]
static const size_t OFF_KT  = 92274688;    // [16][256][512]
static const size_t OFF_SC  = 100663296;   // [16][512][512] (16.8 MB) -> end 117440512
static const size_t OFF_AC  = 117440512;   // [16][512][256] (8.4 MB)
static const size_t OFF_LOG = 125829120;   // [64][512][48]  (6.3 MB)
static const size_t OFF_WTF = 132120576;   // [768][256] wh_f^T
static const size_t OFF_WTB = 132907008;   // [768][256] wh_b^T
static const size_t OFF_HST = 133693440;   // 4 * [64][256] f32 GRU state
// end 133955584 (~128 MiB)

// ---------------------------------------------------------------------------
__global__ __launch_bounds__(256) void zero_k(f32* __restrict__ p, int n) {
  int i = blockIdx.x * 256 + threadIdx.x;
  if (i < n) p[i] = 0.f;
}

// wh transpose: [256][768] -> [768][256]
__global__ __launch_bounds__(256) void transpose_wh_k(
    const f32* __restrict__ whf, const f32* __restrict__ whb,
    f32* __restrict__ wtf, f32* __restrict__ wtb) {
  int o = blockIdx.x * 256 + threadIdx.x;           // 0..196607
  const f32* in = blockIdx.y ? whb : whf;
  f32* out = blockIdx.y ? wtb : wtf;
  int j = o >> 8, d = o & 255;
  out[o] = in[d * 768 + j];
}

// k transpose (one batch chunk): [16][512][256] (b,s,d) -> [16][256][512]
__global__ __launch_bounds__(256) void transpose_k_k(
    const f32* __restrict__ in, f32* __restrict__ out) {
  __shared__ f32 tile[32][33];
  int b = blockIdx.z;
  int s0 = blockIdx.x * 32, d0 = blockIdx.y * 32;
  int x = threadIdx.x & 31;
  int y0 = threadIdx.x >> 5;                        // 0..7
  for (int y = y0; y < 32; y += 8)
    tile[y][x] = in[((size_t)b * 512 + s0 + y) * 256 + d0 + x];
  __syncthreads();
  for (int y = y0; y < 32; y += 8)
    out[((size_t)b * 256 + d0 + y) * 512 + s0 + x] = tile[x][y];
}

// ---------------------------------------------------------------------------
// generic fp32 tiled GEMM, 64x64 tile, K-step 32, 256 threads, 4x4 per thread
enum { GM_PX = 0, GM_QKV = 1, GM_SC = 2, GM_AV = 3, GM_LG = 4 };

template <int MODE>
__global__ __launch_bounds__(256) void gemm_t(
    const f32* __restrict__ A, const f32* __restrict__ Bm, f32* __restrict__ C,
    const f32* __restrict__ bias, const int* __restrict__ xi,
    const f32* __restrict__ hfp, const f32* __restrict__ hbp,
    int N, int K, int rev, int b0, int tbase) {
  const int m0 = blockIdx.y * 64;
  const int n0 = blockIdx.x * 64;
  const int bz = blockIdx.z;
  const int tid = threadIdx.x;
  __shared__ f32 As[32][68];
  __shared__ f32 Bs[32][68];
  f32 acc[4][4] = {};
  const int rowl = tid >> 2;          // 0..63
  const int kq = (tid & 3) * 8;       // 0,8,16,24
  const int nl = tid & 63;
  const int kg = (tid >> 6) * 8;      // 0,8,16,24

  for (int k0 = 0; k0 < K; k0 += 32) {
    // ---- stage A tile (64 rows x 32 k), 8 contiguous floats per thread ----
    {
      const int r = m0 + rowl;
      const f32* src = nullptr;
      if constexpr (MODE == GM_PX) {
        int tl = r >> 6, b = r & 63;            // row = tl*64 + b (chunk-local)
        int tg = tbase + tl;                    // global time
        int ts = rev ? (511 - tg) : tg;
        src = A + (size_t)xi[b * 512 + ts] * 256 + k0 + kq;  // A = embed table
      } else if constexpr (MODE == GM_QKV) {
        int bl = r >> 9, t = r & 511;           // row = bl*512 + t (chunk-local)
        int b = b0 + bl;
        int kk = k0 + kq;
        src = (kk < 256) ? hfp + ((size_t)(t * 64 + b)) * 256 + kk
                         : hbp + ((size_t)((511 - t) * 64 + b)) * 256 + (kk - 256);
      } else if constexpr (MODE == GM_SC) {
        src = A + ((size_t)(bz * 512 + r)) * 256 + k0 + kq;  // A = q_c
      } else if constexpr (MODE == GM_AV) {
        src = A + ((size_t)(bz * 512 + r)) * 512 + k0 + kq;  // A = softmaxed sc_c
      } else {
        src = A + (size_t)r * 256 + k0 + kq;                 // A = a_c (chunk-local)
      }
      float4 u = *(const float4*)src;
      float4 w = *(const float4*)(src + 4);
      As[kq + 0][rowl] = u.x; As[kq + 1][rowl] = u.y;
      As[kq + 2][rowl] = u.z; As[kq + 3][rowl] = u.w;
      As[kq + 4][rowl] = w.x; As[kq + 5][rowl] = w.y;
      As[kq + 6][rowl] = w.z; As[kq + 7][rowl] = w.w;
    }
    // ---- stage B tile (32 k x 64 n), coalesced along n ----
#pragma unroll
    for (int j = 0; j < 8; ++j) {
      int kk = k0 + kg + j;
      f32 vb;
      if constexpr (MODE == GM_PX)       vb = Bm[(size_t)kk * 768 + n0 + nl];
      else if constexpr (MODE == GM_QKV) vb = Bm[(size_t)kk * 256 + n0 + nl];
      else if constexpr (MODE == GM_SC)  vb = Bm[((size_t)bz * 256 + kk) * 512 + n0 + nl];
      else if constexpr (MODE == GM_AV)  vb = Bm[((size_t)bz * 512 + kk) * 256 + n0 + nl];
      else vb = (n0 + nl < N) ? Bm[(size_t)kk * 48 + n0 + nl] : 0.f;
      Bs[kg + j][nl] = vb;
    }
    __syncthreads();
    const int tm = (tid & 15) * 4;
    const int tn = (tid >> 4) * 4;
#pragma unroll 8
    for (int kk = 0; kk < 32; ++kk) {
      float4 a4 = *(const float4*)&As[kk][tm];
      float4 b4 = *(const float4*)&Bs[kk][tn];
      acc[0][0] += a4.x * b4.x; acc[0][1] += a4.x * b4.y; acc[0][2] += a4.x * b4.z; acc[0][3] += a4.x * b4.w;
      acc[1][0] += a4.y * b4.x; acc[1][1] += a4.y * b4.y; acc[1][2] += a4.y * b4.z; acc[1][3] += a4.y * b4.w;
      acc[2][0] += a4.z * b4.x; acc[2][1] += a4.z * b4.y; acc[2][2] += a4.z * b4.z; acc[2][3] += a4.z * b4.w;
      acc[3][0] += a4.w * b4.x; acc[3][1] += a4.w * b4.y; acc[3][2] += a4.w * b4.z; acc[3][3] += a4.w * b4.w;
    }
    __syncthreads();
  }
  // ---- epilogue ----
  const int tm = (tid & 15) * 4;
  const int tn = (tid >> 4) * 4;
#pragma unroll
  for (int i = 0; i < 4; ++i) {
    int r = m0 + tm + i;
    float4 o;
    o.x = acc[i][0] + (bias ? bias[n0 + tn + 0] : 0.f);
    o.y = acc[i][1] + (bias ? bias[n0 + tn + 1] : 0.f);
    o.z = acc[i][2] + (bias ? bias[n0 + tn + 2] : 0.f);
    o.w = acc[i][3] + (bias ? bias[n0 + tn + 3] : 0.f);
    if constexpr (MODE == GM_PX)       *(float4*)&C[(size_t)r * 768 + n0 + tn] = o;
    else if constexpr (MODE == GM_QKV) *(float4*)&C[(size_t)r * 256 + n0 + tn] = o;
    else if constexpr (MODE == GM_SC)  *(float4*)&C[((size_t)bz * 512 + r) * 512 + n0 + tn] = o;
    else if constexpr (MODE == GM_AV)  *(float4*)&C[((size_t)bz * 512 + r) * 256 + n0 + tn] = o;
    else { if (n0 + tn < 48) *(float4*)&C[((size_t)(b0 * 512) + r) * 48 + n0 + tn] = o; }
  }
}

// ---------------------------------------------------------------------------
// one GRU time-step, both directions. grid = 128 blocks (dir = blk>>6),
// each block owns 4 h-columns for all 64 batch rows.
__global__ __launch_bounds__(256) void gru_step(
    const f32* __restrict__ pxf, const f32* __restrict__ pxb,
    const f32* __restrict__ wtf, const f32* __restrict__ wtb,
    const f32* __restrict__ b_f, const f32* __restrict__ b_b,
    f32* __restrict__ hst, f32* __restrict__ hfseq, f32* __restrict__ hbseq,
    int t) {
  __shared__ f32 hl[BB * DD];  // XOR-swizzled [d][b]: hl[d*64 + (b^(d&63))]
  const int dir = blockIdx.x >> 6;
  const int cg = blockIdx.x & 63;
  const int tid = threadIdx.x;
  const f32* px = (dir ? pxb : pxf) + (size_t)(t & (CHT - 1)) * BB * 768;
  const f32* wT = dir ? wtb : wtf;
  const f32* bh = (dir ? b_b : b_f) + 768;
  f32* hcur = hst + (size_t)(dir * 2 + (t & 1)) * BB * DD;
  f32* hnxt = hst + (size_t)(dir * 2 + ((t + 1) & 1)) * BB * DD;
  f32* hseq = (dir ? hbseq : hfseq) + (size_t)t * BB * DD;

  // stage h transposed+swizzled; global reads coalesced, LDS conflict-free
#pragma unroll 8
  for (int j = 0; j < 64; ++j)  // d = tid, b = j
    hl[tid * 64 + (j ^ (tid & 63))] = hcur[j * 256 + tid];
  __syncthreads();

  const int b = tid & 63;
  const int c = tid >> 6;       // wave-uniform
  const int col = cg * 4 + c;   // wave-uniform h column
  const f32* wz = wT + (size_t)(col) * DD;
  const f32* wr = wT + (size_t)(256 + col) * DD;
  const f32* wh = wT + (size_t)(512 + col) * DD;
  f32 az = 0.f, ar = 0.f, ah = 0.f;
#pragma unroll 4
  for (int d = 0; d < DD; d += 4) {
    float4 z4 = *(const float4*)(wz + d);
    float4 r4 = *(const float4*)(wr + d);
    float4 h4 = *(const float4*)(wh + d);
    f32 h0 = hl[(d + 0) * 64 + (b ^ ((d + 0) & 63))];
    f32 h1 = hl[(d + 1) * 64 + (b ^ ((d + 1) & 63))];
    f32 h2 = hl[(d + 2) * 64 + (b ^ ((d + 2) & 63))];
    f32 h3 = hl[(d + 3) * 64 + (b ^ ((d + 3) & 63))];
    az += z4.x * h0 + z4.y * h1 + z4.z * h2 + z4.w * h3;
    ar += r4.x * h0 + r4.y * h1 + r4.z * h2 + r4.w * h3;
    ah += h4.x * h0 + h4.y * h1 + h4.z * h2 + h4.w * h3;
  }
  const f32 xz = px[(size_t)b * 768 + col];
  const f32 xr = px[(size_t)b * 768 + 256 + col];
  const f32 xh = px[(size_t)b * 768 + 512 + col];
  const f32 hz = az + bh[col];
  const f32 hr = ar + bh[256 + col];
  const f32 hh = ah + bh[512 + col];
  const f32 z = 1.f / (1.f + expf(-(xz + hz)));
  const f32 r = 1.f / (1.f + expf(-(xr + hr)));
  const f32 hc = tanhf(xh + r * hh);
  const f32 hold = hl[col * 64 + (b ^ (col & 63))];
  const f32 hn = z * hold + (1.f - z) * hc;
  hnxt[b * DD + col] = hn;
  hseq[(size_t)b * DD + col] = hn;
}

// ---------------------------------------------------------------------------
// row softmax over 512 elements, one block per row
__global__ __launch_bounds__(256) void softmax_rows(f32* __restrict__ p) {
  size_t row = blockIdx.x;
  f32* pr = p + row * 512;
  int tid = threadIdx.x;
  f32 v0 = pr[tid], v1 = pr[tid + 256];
  f32 m = fmaxf(v0, v1);
  for (int o = 32; o; o >>= 1) m = fmaxf(m, __shfl_xor(m, o));
  __shared__ f32 red[4];
  __shared__ f32 red2[4];
  if ((tid & 63) == 0) red[tid >> 6] = m;
  __syncthreads();
  m = fmaxf(fmaxf(red[0], red[1]), fmaxf(red[2], red[3]));
  f32 e0 = expf(v0 - m), e1 = expf(v1 - m);
  f32 s = e0 + e1;
  for (int o = 32; o; o >>= 1) s += __shfl_xor(s, o);
  if ((tid & 63) == 0) red2[tid >> 6] = s;
  __syncthreads();
  s = red2[0] + red2[1] + red2[2] + red2[3];
  f32 inv = 1.f / s;
  pr[tid] = e0 * inv;
  pr[tid + 256] = e1 * inv;
}

// ---------------------------------------------------------------------------
// CRF log-likelihood, one block (1 wave) per batch element
__global__ __launch_bounds__(64) void crf_ll_k(
    const f32* __restrict__ logits, const int* __restrict__ y,
    const int* __restrict__ seq_len, const f32* __restrict__ trans,
    f32* __restrict__ out) {
  const int b = blockIdx.x, tid = threadIdx.x;
  __shared__ f32 tr[NN][NN];
  __shared__ f32 al[2][NN];
  for (int i = tid; i < NN * NN; i += 64) tr[i / NN][i % NN] = trans[i];
  const f32* em = logits + (size_t)b * TT * NN;
  const int L = seq_len[b];
  if (tid < NN) al[0][tid] = em[tid];
  __syncthreads();
  int cur = 0;
  for (int t = 1; t < TT; ++t) {
    if (t >= L) break;  // mask is monotonic: alpha frozen afterwards
    if (tid < NN) {
      f32 m = -1e30f;
      for (int i = 0; i < NN; ++i) m = fmaxf(m, al[cur][i] + tr[i][tid]);
      f32 s = 0.f;
      for (int i = 0; i < NN; ++i) s += expf(al[cur][i] + tr[i][tid] - m);
      al[cur ^ 1][tid] = m + logf(s) + em[t * NN + tid];
    }
    __syncthreads();
    cur ^= 1;
  }
  f32 us = 0.f, ts = 0.f;
  for (int t = tid; t < TT; t += 64) {
    if (t < L) {
      us += em[t * NN + y[b * TT + t]];
      if (t >= 1) ts += tr[y[b * TT + t - 1]][y[b * TT + t]];
    }
  }
  for (int o = 32; o; o >>= 1) { us += __shfl_xor(us, o); ts += __shfl_xor(ts, o); }
  if (tid == 0) {
    f32 m = -1e30f;
    for (int i = 0; i < NN; ++i) m = fmaxf(m, al[cur][i]);
    f32 s = 0.f;
    for (int i = 0; i < NN; ++i) s += expf(al[cur][i] - m);
    out[(size_t)BB * TT + b] = us + ts - (m + logf(s));
  }
}

// ---------------------------------------------------------------------------
// CRF Viterbi decode, one block (1 wave) per batch element; bp kept in LDS
__global__ __launch_bounds__(64) void crf_decode_k(
    const f32* __restrict__ logits, const int* __restrict__ seq_len,
    const f32* __restrict__ trans, f32* __restrict__ out) {
  const int b = blockIdx.x, tid = threadIdx.x;
  __shared__ f32 tr[NN][NN];
  __shared__ f32 al[2][NN];
  __shared__ unsigned char bp[TT - 1][NN];
  __shared__ unsigned char pr[TT];
  for (int i = tid; i < NN * NN; i += 64) tr[i / NN][i % NN] = trans[i];
  const f32* em = logits + (size_t)b * TT * NN;
  const int L = seq_len[b];
  if (tid < NN) al[0][tid] = em[tid];
  __syncthreads();
  int cur = 0;
  for (int t = 1; t < TT; ++t) {
    if (tid < NN) {
      if (t < L) {
        f32 m = -1e30f; int arg = 0;
        for (int i = 0; i < NN; ++i) {
          f32 v = al[cur][i] + tr[i][tid];
          if (v > m) { m = v; arg = i; }  // first max, matches jnp.argmax
        }
        al[cur ^ 1][tid] = m + em[t * NN + tid];
        bp[t - 1][tid] = (unsigned char)arg;
      } else {
        al[cur ^ 1][tid] = al[cur][tid];
        bp[t - 1][tid] = (unsigned char)tid;  // identity beyond seq end
      }
    }
    __syncthreads();
    cur ^= 1;
  }
  if (tid == 0) {
    f32 m = -1e30f; int last = 0;
    for (int i = 0; i < NN; ++i)
      if (al[cur][i] > m) { m = al[cur][i]; last = i; }
    int tag = last;
    for (int t = TT - 2; t >= 0; --t) { pr[t + 1] = (unsigned char)tag; tag = bp[t][tag]; }
    pr[0] = (unsigned char)tag;
  }
  __syncthreads();
  for (int t = tid; t < TT; t += 64)
    out[(size_t)b * TT + t] = (f32)pr[t];  // pred emitted as float32
}

// ---------------------------------------------------------------------------
extern "C" void kernel_launch(void* const* d_in, const int* in_sizes, int n_in,
                              void* d_out, int out_size, void* d_ws, size_t ws_size,
                              hipStream_t stream) {
  const int* x       = (const int*)d_in[0];
  const int* y       = (const int*)d_in[1];
  const int* seq_len = (const int*)d_in[2];
  const f32* embed   = (const f32*)d_in[3];
  const f32* wx_f    = (const f32*)d_in[4];
  const f32* wh_f    = (const f32*)d_in[5];
  const f32* b_f     = (const f32*)d_in[6];
  const f32* wx_b    = (const f32*)d_in[7];
  const f32* wh_b    = (const f32*)d_in[8];
  const f32* b_b     = (const f32*)d_in[9];
  const f32* wq      = (const f32*)d_in[10];
  const f32* bq      = (const f32*)d_in[11];
  const f32* wk      = (const f32*)d_in[12];
  const f32* bk      = (const f32*)d_in[13];
  const f32* wv      = (const f32*)d_in[14];
  const f32* bv      = (const f32*)d_in[15];
  const f32* wt      = (const f32*)d_in[16];
  const f32* bt      = (const f32*)d_in[17];
  const f32* trans   = (const f32*)d_in[18];
  f32* out = (f32*)d_out;

  char* ws = (char*)d_ws;
  f32* hf   = (f32*)(ws + OFF_HF);
  f32* hb   = (f32*)(ws + OFF_HB);
  f32* pxf  = (f32*)(ws + OFF_PXF);
  f32* pxb  = (f32*)(ws + OFF_PXB);
  f32* qc   = (f32*)(ws + OFF_QC);
  f32* kc   = (f32*)(ws + OFF_KC);
  f32* vc   = (f32*)(ws + OFF_VC);
  f32* kT   = (f32*)(ws + OFF_KT);
  f32* sc   = (f32*)(ws + OFF_SC);
  f32* ac   = (f32*)(ws + OFF_AC);
  f32* lg   = (f32*)(ws + OFF_LOG);
  f32* wtf  = (f32*)(ws + OFF_WTF);
  f32* wtb  = (f32*)(ws + OFF_WTB);
  f32* hst  = (f32*)(ws + OFF_HST);

  // zero GRU state (both directions, both ping-pong buffers): 65536 floats
  zero_k<<<256, 256, 0, stream>>>(hst, 4 * BB * DD);

  // transpose recurrent weights to [j][d]
  transpose_wh_k<<<dim3(768, 2), 256, 0, stream>>>(wh_f, wh_b, wtf, wtb);

  // ---- GRU phase: px in 4 time-chunks of 128, interleaved with the scan ----
  for (int tc = 0; tc < TT / CHT; ++tc) {
    gemm_t<GM_PX><<<dim3(12, CHT), 256, 0, stream>>>(
        embed, wx_f, pxf, b_f, x, nullptr, nullptr, 768, 256, 0, 0, tc * CHT);
    gemm_t<GM_PX><<<dim3(12, CHT), 256, 0, stream>>>(
        embed, wx_b, pxb, b_b, x, nullptr, nullptr, 768, 256, 1, 0, tc * CHT);
    for (int tl = 0; tl < CHT; ++tl)
      gru_step<<<128, 256, 0, stream>>>(pxf, pxb, wtf, wtb, b_f, b_b,
                                        hst, hf, hb, tc * CHT + tl);
  }

  // ---- attention + logits in 4 batch-chunks of 16 ----
  for (int bc = 0; bc < BB / CHB; ++bc) {
    const int b0 = bc * CHB;
    gemm_t<GM_QKV><<<dim3(4, CHB * 8), 256, 0, stream>>>(
        nullptr, wq, qc, bq, nullptr, hf, hb, 256, 512, 0, b0, 0);
    gemm_t<GM_QKV><<<dim3(4, CHB * 8), 256, 0, stream>>>(
        nullptr, wk, kc, bk, nullptr, hf, hb, 256, 512, 0, b0, 0);
    gemm_t<GM_QKV><<<dim3(4, CHB * 8), 256, 0, stream>>>(
        nullptr, wv, vc, bv, nullptr, hf, hb, 256, 512, 0, b0, 0);
    transpose_k_k<<<dim3(16, 8, CHB), 256, 0, stream>>>(kc, kT);
    gemm_t<GM_SC><<<dim3(8, 8, CHB), 256, 0, stream>>>(
        qc, kT, sc, nullptr, nullptr, nullptr, nullptr, 512, 256, 0, 0, 0);
    softmax_rows<<<CHB * 512, 256, 0, stream>>>(sc);
    gemm_t<GM_AV><<<dim3(4, 8, CHB), 256, 0, stream>>>(
        sc, vc, ac, nullptr, nullptr, nullptr, nullptr, 256, 512, 0, 0, 0);
    gemm_t<GM_LG><<<dim3(1, CHB * 8), 256, 0, stream>>>(
        ac, wt, lg, bt, nullptr, nullptr, nullptr, 48, 256, 0, b0, 0);
  }

  // ---- CRF ----
  crf_ll_k<<<BB, 64, 0, stream>>>(lg, y, seq_len, trans, out);
  crf_decode_k<<<BB, 64, 0, stream>>>(lg, seq_len, trans, out);
}

// Round 3
// 7574.940 us; speedup vs baseline: 1.1023x; 1.1023x over previous
//
#include <hip/hip_runtime.h>
#include <math.h>

typedef float f32;
typedef short short8 __attribute__((ext_vector_type(8)));
typedef float f32x4 __attribute__((ext_vector_type(4)));

#define TT 512
#define BB 64
#define DD 256
#define NN 48
#define CHT 128   // time chunk for px
#define CHB 16    // batch chunk for attention

// ===== workspace offsets (bytes). Peak ~110 MB =====
static const size_t OFF_HBF_F = 0;                          // [512][64][256] bf16
static const size_t OFF_HBF_B = OFF_HBF_F + 16777216;
static const size_t OFF_ARENA = OFF_HBF_B + 16777216;       // 33,554,432
// GRU phase (px fp32 chunks):
static const size_t OFF_PXF = OFF_ARENA;                    // [128][64][768] f32
static const size_t OFF_PXB = OFF_PXF + 25165824;           // end 83,886,080
// ATTN phase (aliases arena):
static const size_t OFF_QBF = OFF_ARENA;                    // [16][512][256] bf16
static const size_t OFF_KBF = OFF_QBF + 4194304;
static const size_t OFF_VBF = OFF_KBF + 4194304;
static const size_t OFF_VT  = OFF_VBF + 4194304;            // [16][256][512] bf16
static const size_t OFF_SC  = OFF_VT  + 4194304;            // [16][512][512] f32
static const size_t OFF_WBF = OFF_SC  + 16777216;           // [16][512][512] bf16
static const size_t OFF_ABF = OFF_WBF + 8388608;            // [16][512][256] bf16
static const size_t OFF_LG  = OFF_ARENA + 50331648;         // [64][512][48] f32
static const size_t OFF_EBF = OFF_LG + 6291456;             // [32000][256] bf16
static const size_t OFF_WHTF= OFF_EBF + 16384000;           // [768][256] f32
static const size_t OFF_WHTB= OFF_WHTF + 786432;
static const size_t OFF_WXTF= OFF_WHTB + 786432;            // [768][256] bf16
static const size_t OFF_WXTB= OFF_WXTF + 393216;
static const size_t OFF_WQT = OFF_WXTB + 393216;            // [256][512] bf16
static const size_t OFF_WKT = OFF_WQT + 262144;
static const size_t OFF_WVT = OFF_WKT + 262144;
static const size_t OFF_WTT = OFF_WVT + 262144;             // [48][256] bf16
static const size_t OFF_HST = OFF_WTT + 24576;              // 4*[64][256] f32
// end ~110.0 MB

__device__ __forceinline__ ushort f2bf(f32 f) {
  union { f32 f; unsigned u; } v; v.f = f;
  unsigned r = v.u + 0x7fffu + ((v.u >> 16) & 1u);   // RNE
  return (ushort)(r >> 16);
}

// ---------------------------------------------------------------------------
__global__ __launch_bounds__(256) void zero_k(f32* __restrict__ p, int n) {
  int i = blockIdx.x * 256 + threadIdx.x;
  if (i < n) p[i] = 0.f;
}

// wh transpose fp32: [256][768] -> [768][256]
__global__ __launch_bounds__(256) void transpose_wh_k(
    const f32* __restrict__ whf, const f32* __restrict__ whb,
    f32* __restrict__ wtf, f32* __restrict__ wtb) {
  int o = blockIdx.x * 256 + threadIdx.x;
  const f32* in = blockIdx.y ? whb : whf;
  f32* out = blockIdx.y ? wtb : wtf;
  int j = o >> 8, d = o & 255;
  out[o] = in[d * 768 + j];
}

// generic transpose+convert: in f32 [P][Q] -> out bf16 [Q][P], P = 1<<PL2
template <int PL2>
__global__ __launch_bounds__(256) void tconv_k(
    const f32* __restrict__ in, ushort* __restrict__ out, int total, int Q) {
  int o = blockIdx.x * 256 + threadIdx.x;
  if (o >= total) return;
  int q = o >> PL2, p = o & ((1 << PL2) - 1);
  out[o] = f2bf(in[(size_t)p * Q + q]);
}

// embed table f32 -> bf16
__global__ __launch_bounds__(256) void conv_embed_k(
    const f32* __restrict__ in, ushort* __restrict__ out, int n4) {
  int i = blockIdx.x * 256 + threadIdx.x;
  if (i >= n4) return;
  float4 v = ((const float4*)in)[i];
  ushort4 o;
  o.x = f2bf(v.x); o.y = f2bf(v.y); o.z = f2bf(v.z); o.w = f2bf(v.w);
  ((ushort4*)out)[i] = o;
}

// v transpose bf16 (per batch chunk): [16][512][256] -> [16][256][512]
__global__ __launch_bounds__(256) void tr_v_k(
    const ushort* __restrict__ in, ushort* __restrict__ out) {
  __shared__ ushort tile[32][33];
  int b = blockIdx.z;
  int s0 = blockIdx.x * 32, d0 = blockIdx.y * 32;
  int xc = threadIdx.x & 31, y0 = threadIdx.x >> 5;
  for (int yy = y0; yy < 32; yy += 8)
    tile[yy][xc] = in[((size_t)b * 512 + s0 + yy) * 256 + d0 + xc];
  __syncthreads();
  for (int yy = y0; yy < 32; yy += 8)
    out[((size_t)b * 256 + d0 + yy) * 512 + s0 + xc] = tile[xc][yy];
}

// ---------------------------------------------------------------------------
// bf16 MFMA GEMM: 128x128 block tile, BK=32, 256 thr (4 waves, 64x64 each).
// LDS: A and B^T staged [row][k], rows padded to 40 shorts (80B).
enum { GM_PX = 0, GM_QKV = 1, GM_SC = 2, GM_AV = 3, GM_LG = 4 };

template <int MODE>
__global__ __launch_bounds__(256) void mgemm(
    const ushort* __restrict__ Aa, const ushort* __restrict__ Ab,
    const ushort* __restrict__ Bt,
    f32* __restrict__ Cf, ushort* __restrict__ Cb,
    const f32* __restrict__ bias, const int* __restrict__ xi,
    int Ndim, int K, int rev, int b0, int tbase) {
  const int m0 = blockIdx.y * 128;
  const int n0 = blockIdx.x * 128;
  const int bz = blockIdx.z;
  const int tid = threadIdx.x;
  const int l = tid & 63, w = tid >> 6;
  const int wr = w >> 1, wc = w & 1;
  __shared__ __align__(16) short Al[128 * 40];
  __shared__ __align__(16) short Bl[128 * 40];
  f32x4 acc[4][4] = {};

  // ---- hoisted A row base (per-thread staging row) ----
  const int rowa = tid >> 1;
  const int kha = (tid & 1) * 16;
  const int rA = m0 + rowa;
  const ushort* aBase = nullptr;
  const ushort* aBase2 = nullptr;
  if constexpr (MODE == GM_PX) {
    int tl = rA >> 6, b = rA & 63;
    int tg = tbase + tl;
    int ts = rev ? (511 - tg) : tg;
    aBase = Aa + (size_t)xi[b * 512 + ts] * 256;
  } else if constexpr (MODE == GM_QKV) {
    int bl = rA >> 9, t = rA & 511;
    int b = b0 + bl;
    aBase = Aa + ((size_t)(t * 64 + b)) * 256;            // fwd half
    aBase2 = Ab + ((size_t)((511 - t) * 64 + b)) * 256;   // bwd half
  } else if constexpr (MODE == GM_SC) {
    aBase = Aa + ((size_t)(bz * 512 + rA)) * 256;
  } else if constexpr (MODE == GM_AV) {
    aBase = Aa + ((size_t)(bz * 512 + rA)) * 512;
  } else {
    aBase = Aa + (size_t)rA * 256;
  }
  // ---- hoisted B^T row base ----
  const int rowb = tid >> 1;
  const int khb = (tid & 1) * 16;
  int rowg = n0 + rowb;
  if constexpr (MODE == GM_SC) rowg += bz * 512;
  if constexpr (MODE == GM_AV) rowg += bz * 256;
  const ushort* bBase = Bt + (size_t)rowg * K;
  const bool bValid = (MODE != GM_LG) || (n0 + rowb < Ndim);

  for (int k0 = 0; k0 < K; k0 += 32) {
    // stage A (128 rows x 32 k): 16 bf16 per thread
    {
      int kk = k0 + kha;
      const ushort* src;
      if constexpr (MODE == GM_QKV)
        src = (kk < 256) ? aBase + kk : aBase2 + (kk - 256);
      else
        src = aBase + kk;
      uint4 a0 = *(const uint4*)src;
      uint4 a1 = *(const uint4*)(src + 8);
      *(uint4*)&Al[rowa * 40 + kha] = a0;
      *(uint4*)&Al[rowa * 40 + kha + 8] = a1;
    }
    // stage B^T (128 rows x 32 k)
    {
      uint4 v0 = make_uint4(0, 0, 0, 0), v1 = make_uint4(0, 0, 0, 0);
      if (bValid) {
        const ushort* src = bBase + k0 + khb;
        v0 = *(const uint4*)src;
        v1 = *(const uint4*)(src + 8);
      }
      *(uint4*)&Bl[rowb * 40 + khb] = v0;
      *(uint4*)&Bl[rowb * 40 + khb + 8] = v1;
    }
    __syncthreads();
    const int fr = l & 15, fg = l >> 4;
    short8 af[4], bfr[4];
#pragma unroll
    for (int mf = 0; mf < 4; ++mf)
      af[mf] = *(const short8*)&Al[(wr * 64 + mf * 16 + fr) * 40 + fg * 8];
#pragma unroll
    for (int nf = 0; nf < 4; ++nf)
      bfr[nf] = *(const short8*)&Bl[(wc * 64 + nf * 16 + fr) * 40 + fg * 8];
#pragma unroll
    for (int mf = 0; mf < 4; ++mf)
#pragma unroll
      for (int nf = 0; nf < 4; ++nf)
        acc[mf][nf] = __builtin_amdgcn_mfma_f32_16x16x32_bf16(
            af[mf], bfr[nf], acc[mf][nf], 0, 0, 0);
    __syncthreads();
  }

  // ---- epilogue (C/D: col=l&15, row=(l>>4)*4+reg  [m89]) ----
  const int fr = l & 15, fq = l >> 4;
#pragma unroll
  for (int mf = 0; mf < 4; ++mf) {
#pragma unroll
    for (int nf = 0; nf < 4; ++nf) {
      int col = n0 + wc * 64 + nf * 16 + fr;
      f32 bs = 0.f;
      if (bias && col < Ndim) bs = bias[col];
#pragma unroll
      for (int rg = 0; rg < 4; ++rg) {
        int row = m0 + wr * 64 + mf * 16 + fq * 4 + rg;
        f32 vv = acc[mf][nf][rg] + bs;
        if constexpr (MODE == GM_PX)
          Cf[(size_t)row * 768 + col] = vv;
        else if constexpr (MODE == GM_QKV)
          Cb[(size_t)row * 256 + col] = f2bf(vv);
        else if constexpr (MODE == GM_SC)
          Cf[((size_t)bz * 512 + row) * 512 + col] = vv;
        else if constexpr (MODE == GM_AV)
          Cb[((size_t)bz * 512 + row) * 256 + col] = f2bf(vv);
        else {
          if (col < Ndim) Cf[((size_t)b0 * 512 + row) * 48 + col] = vv;
        }
      }
    }
  }
}

// ---------------------------------------------------------------------------
// one GRU time-step, both directions; writes bf16 hidden sequence
__global__ __launch_bounds__(256) void gru_step(
    const f32* __restrict__ pxf, const f32* __restrict__ pxb,
    const f32* __restrict__ wtf, const f32* __restrict__ wtb,
    const f32* __restrict__ b_f, const f32* __restrict__ b_b,
    f32* __restrict__ hst, ushort* __restrict__ hfbf, ushort* __restrict__ hbbf,
    int t) {
  __shared__ f32 hl[BB * DD];  // XOR-swizzled [d][b]
  const int dir = blockIdx.x >> 6;
  const int cg = blockIdx.x & 63;
  const int tid = threadIdx.x;
  const f32* px = (dir ? pxb : pxf) + (size_t)(t & (CHT - 1)) * BB * 768;
  const f32* wT = dir ? wtb : wtf;
  const f32* bh = (dir ? b_b : b_f) + 768;
  f32* hcur = hst + (size_t)(dir * 2 + (t & 1)) * BB * DD;
  f32* hnxt = hst + (size_t)(dir * 2 + ((t + 1) & 1)) * BB * DD;
  ushort* hseq = (dir ? hbbf : hfbf) + (size_t)t * BB * DD;

#pragma unroll 8
  for (int j = 0; j < 64; ++j)
    hl[tid * 64 + (j ^ (tid & 63))] = hcur[j * 256 + tid];
  __syncthreads();

  const int b = tid & 63;
  const int c = tid >> 6;
  const int col = cg * 4 + c;
  const f32* wz = wT + (size_t)(col)*DD;
  const f32* wr = wT + (size_t)(256 + col) * DD;
  const f32* wh = wT + (size_t)(512 + col) * DD;
  f32 az = 0.f, ar = 0.f, ah = 0.f;
#pragma unroll 4
  for (int d = 0; d < DD; d += 4) {
    float4 z4 = *(const float4*)(wz + d);
    float4 r4 = *(const float4*)(wr + d);
    float4 h4 = *(const float4*)(wh + d);
    f32 h0 = hl[(d + 0) * 64 + (b ^ ((d + 0) & 63))];
    f32 h1 = hl[(d + 1) * 64 + (b ^ ((d + 1) & 63))];
    f32 h2 = hl[(d + 2) * 64 + (b ^ ((d + 2) & 63))];
    f32 h3 = hl[(d + 3) * 64 + (b ^ ((d + 3) & 63))];
    az += z4.x * h0 + z4.y * h1 + z4.z * h2 + z4.w * h3;
    ar += r4.x * h0 + r4.y * h1 + r4.z * h2 + r4.w * h3;
    ah += h4.x * h0 + h4.y * h1 + h4.z * h2 + h4.w * h3;
  }
  const f32 xz = px[(size_t)b * 768 + col];
  const f32 xr = px[(size_t)b * 768 + 256 + col];
  const f32 xh = px[(size_t)b * 768 + 512 + col];
  const f32 hz = az + bh[col];
  const f32 hr = ar + bh[256 + col];
  const f32 hh = ah + bh[512 + col];
  const f32 z = 1.f / (1.f + expf(-(xz + hz)));
  const f32 r = 1.f / (1.f + expf(-(xr + hr)));
  const f32 hc = tanhf(xh + r * hh);
  const f32 hold = hl[col * 64 + (b ^ (col & 63))];
  const f32 hn = z * hold + (1.f - z) * hc;
  hnxt[b * DD + col] = hn;
  hseq[(size_t)b * DD + col] = f2bf(hn);
}

// ---------------------------------------------------------------------------
// row softmax over 512 elems (f32 in, bf16 out), one block per row
__global__ __launch_bounds__(256) void softmax_rows(
    const f32* __restrict__ p, ushort* __restrict__ o) {
  size_t row = blockIdx.x;
  const f32* pr = p + row * 512;
  int tid = threadIdx.x;
  f32 v0 = pr[tid], v1 = pr[tid + 256];
  f32 m = fmaxf(v0, v1);
  for (int off = 32; off; off >>= 1) m = fmaxf(m, __shfl_xor(m, off));
  __shared__ f32 red[4];
  __shared__ f32 red2[4];
  if ((tid & 63) == 0) red[tid >> 6] = m;
  __syncthreads();
  m = fmaxf(fmaxf(red[0], red[1]), fmaxf(red[2], red[3]));
  f32 e0 = expf(v0 - m), e1 = expf(v1 - m);
  f32 s = e0 + e1;
  for (int off = 32; off; off >>= 1) s += __shfl_xor(s, off);
  if ((tid & 63) == 0) red2[tid >> 6] = s;
  __syncthreads();
  s = red2[0] + red2[1] + red2[2] + red2[3];
  f32 inv = 1.f / s;
  o[row * 512 + tid] = f2bf(e0 * inv);
  o[row * 512 + tid + 256] = f2bf(e1 * inv);
}

// ---------------------------------------------------------------------------
// CRF log-likelihood, one block (1 wave) per batch element
__global__ __launch_bounds__(64) void crf_ll_k(
    const f32* __restrict__ logits, const int* __restrict__ y,
    const int* __restrict__ seq_len, const f32* __restrict__ trans,
    f32* __restrict__ out) {
  const int b = blockIdx.x, tid = threadIdx.x;
  __shared__ f32 tr[NN][NN];
  __shared__ f32 al[2][NN];
  for (int i = tid; i < NN * NN; i += 64) tr[i / NN][i % NN] = trans[i];
  const f32* em = logits + (size_t)b * TT * NN;
  const int L = seq_len[b];
  if (tid < NN) al[0][tid] = em[tid];
  __syncthreads();
  int cur = 0;
  for (int t = 1; t < TT; ++t) {
    if (t >= L) break;
    if (tid < NN) {
      f32 m = -1e30f;
      for (int i = 0; i < NN; ++i) m = fmaxf(m, al[cur][i] + tr[i][tid]);
      f32 s = 0.f;
      for (int i = 0; i < NN; ++i) s += expf(al[cur][i] + tr[i][tid] - m);
      al[cur ^ 1][tid] = m + logf(s) + em[t * NN + tid];
    }
    __syncthreads();
    cur ^= 1;
  }
  f32 us = 0.f, ts = 0.f;
  for (int t = tid; t < TT; t += 64) {
    if (t < L) {
      us += em[t * NN + y[b * TT + t]];
      if (t >= 1) ts += tr[y[b * TT + t - 1]][y[b * TT + t]];
    }
  }
  for (int off = 32; off; off >>= 1) { us += __shfl_xor(us, off); ts += __shfl_xor(ts, off); }
  if (tid == 0) {
    f32 m = -1e30f;
    for (int i = 0; i < NN; ++i) m = fmaxf(m, al[cur][i]);
    f32 s = 0.f;
    for (int i = 0; i < NN; ++i) s += expf(al[cur][i] - m);
    out[(size_t)BB * TT + b] = us + ts - (m + logf(s));
  }
}

// CRF Viterbi decode, one block (1 wave) per batch element
__global__ __launch_bounds__(64) void crf_decode_k(
    const f32* __restrict__ logits, const int* __restrict__ seq_len,
    const f32* __restrict__ trans, f32* __restrict__ out) {
  const int b = blockIdx.x, tid = threadIdx.x;
  __shared__ f32 tr[NN][NN];
  __shared__ f32 al[2][NN];
  __shared__ unsigned char bp[TT - 1][NN];
  __shared__ unsigned char pr[TT];
  for (int i = tid; i < NN * NN; i += 64) tr[i / NN][i % NN] = trans[i];
  const f32* em = logits + (size_t)b * TT * NN;
  const int L = seq_len[b];
  if (tid < NN) al[0][tid] = em[tid];
  __syncthreads();
  int cur = 0;
  for (int t = 1; t < TT; ++t) {
    if (tid < NN) {
      if (t < L) {
        f32 m = -1e30f; int arg = 0;
        for (int i = 0; i < NN; ++i) {
          f32 v = al[cur][i] + tr[i][tid];
          if (v > m) { m = v; arg = i; }
        }
        al[cur ^ 1][tid] = m + em[t * NN + tid];
        bp[t - 1][tid] = (unsigned char)arg;
      } else {
        al[cur ^ 1][tid] = al[cur][tid];
        bp[t - 1][tid] = (unsigned char)tid;
      }
    }
    __syncthreads();
    cur ^= 1;
  }
  if (tid == 0) {
    f32 m = -1e30f; int last = 0;
    for (int i = 0; i < NN; ++i)
      if (al[cur][i] > m) { m = al[cur][i]; last = i; }
    int tag = last;
    for (int t = TT - 2; t >= 0; --t) { pr[t + 1] = (unsigned char)tag; tag = bp[t][tag]; }
    pr[0] = (unsigned char)tag;
  }
  __syncthreads();
  for (int t = tid; t < TT; t += 64)
    out[(size_t)b * TT + t] = (f32)pr[t];
}

// ---------------------------------------------------------------------------
extern "C" void kernel_launch(void* const* d_in, const int* in_sizes, int n_in,
                              void* d_out, int out_size, void* d_ws, size_t ws_size,
                              hipStream_t stream) {
  const int* x       = (const int*)d_in[0];
  const int* y       = (const int*)d_in[1];
  const int* seq_len = (const int*)d_in[2];
  const f32* embed   = (const f32*)d_in[3];
  const f32* wx_f    = (const f32*)d_in[4];
  const f32* wh_f    = (const f32*)d_in[5];
  const f32* b_f     = (const f32*)d_in[6];
  const f32* wx_b    = (const f32*)d_in[7];
  const f32* wh_b    = (const f32*)d_in[8];
  const f32* b_b     = (const f32*)d_in[9];
  const f32* wq      = (const f32*)d_in[10];
  const f32* bq      = (const f32*)d_in[11];
  const f32* wk      = (const f32*)d_in[12];
  const f32* bk      = (const f32*)d_in[13];
  const f32* wv      = (const f32*)d_in[14];
  const f32* bv      = (const f32*)d_in[15];
  const f32* wt      = (const f32*)d_in[16];
  const f32* bt      = (const f32*)d_in[17];
  const f32* trans   = (const f32*)d_in[18];
  f32* out = (f32*)d_out;

  char* ws = (char*)d_ws;
  ushort* hfbf = (ushort*)(ws + OFF_HBF_F);
  ushort* hbbf = (ushort*)(ws + OFF_HBF_B);
  f32* pxf  = (f32*)(ws + OFF_PXF);
  f32* pxb  = (f32*)(ws + OFF_PXB);
  ushort* qbf = (ushort*)(ws + OFF_QBF);
  ushort* kbf = (ushort*)(ws + OFF_KBF);
  ushort* vbf = (ushort*)(ws + OFF_VBF);
  ushort* vT  = (ushort*)(ws + OFF_VT);
  f32* sc   = (f32*)(ws + OFF_SC);
  ushort* wbf = (ushort*)(ws + OFF_WBF);
  ushort* abf = (ushort*)(ws + OFF_ABF);
  f32* lg   = (f32*)(ws + OFF_LG);
  ushort* ebf = (ushort*)(ws + OFF_EBF);
  f32* whtf = (f32*)(ws + OFF_WHTF);
  f32* whtb = (f32*)(ws + OFF_WHTB);
  ushort* wxtf = (ushort*)(ws + OFF_WXTF);
  ushort* wxtb = (ushort*)(ws + OFF_WXTB);
  ushort* wqt = (ushort*)(ws + OFF_WQT);
  ushort* wkt = (ushort*)(ws + OFF_WKT);
  ushort* wvt = (ushort*)(ws + OFF_WVT);
  ushort* wtt = (ushort*)(ws + OFF_WTT);
  f32* hst  = (f32*)(ws + OFF_HST);

  // ---- setup ----
  zero_k<<<256, 256, 0, stream>>>(hst, 4 * BB * DD);
  transpose_wh_k<<<dim3(768, 2), 256, 0, stream>>>(wh_f, wh_b, whtf, whtb);
  conv_embed_k<<<8000, 256, 0, stream>>>(embed, ebf, 2048000);
  tconv_k<8><<<768, 256, 0, stream>>>(wx_f, wxtf, 196608, 768);
  tconv_k<8><<<768, 256, 0, stream>>>(wx_b, wxtb, 196608, 768);
  tconv_k<9><<<512, 256, 0, stream>>>(wq, wqt, 131072, 256);
  tconv_k<9><<<512, 256, 0, stream>>>(wk, wkt, 131072, 256);
  tconv_k<9><<<512, 256, 0, stream>>>(wv, wvt, 131072, 256);
  tconv_k<8><<<48, 256, 0, stream>>>(wt, wtt, 12288, 48);

  // ---- GRU phase: px bf16-MFMA in 4 time-chunks, interleaved with scan ----
  for (int tc = 0; tc < TT / CHT; ++tc) {
    mgemm<GM_PX><<<dim3(6, 64), 256, 0, stream>>>(
        ebf, nullptr, wxtf, pxf, nullptr, b_f, x, 768, 256, 0, 0, tc * CHT);
    mgemm<GM_PX><<<dim3(6, 64), 256, 0, stream>>>(
        ebf, nullptr, wxtb, pxb, nullptr, b_b, x, 768, 256, 1, 0, tc * CHT);
    for (int tl = 0; tl < CHT; ++tl)
      gru_step<<<128, 256, 0, stream>>>(pxf, pxb, whtf, whtb, b_f, b_b,
                                        hst, hfbf, hbbf, tc * CHT + tl);
  }

  // ---- attention + logits, 4 batch chunks of 16, all bf16 MFMA ----
  for (int bc = 0; bc < BB / CHB; ++bc) {
    const int b0 = bc * CHB;
    mgemm<GM_QKV><<<dim3(2, 64), 256, 0, stream>>>(
        hfbf, hbbf, wqt, nullptr, qbf, bq, nullptr, 256, 512, 0, b0, 0);
    mgemm<GM_QKV><<<dim3(2, 64), 256, 0, stream>>>(
        hfbf, hbbf, wkt, nullptr, kbf, bk, nullptr, 256, 512, 0, b0, 0);
    mgemm<GM_QKV><<<dim3(2, 64), 256, 0, stream>>>(
        hfbf, hbbf, wvt, nullptr, vbf, bv, nullptr, 256, 512, 0, b0, 0);
    tr_v_k<<<dim3(16, 8, CHB), 256, 0, stream>>>(vbf, vT);
    // scores: A=q, B^T = k itself (no transpose needed)
    mgemm<GM_SC><<<dim3(4, 4, CHB), 256, 0, stream>>>(
        qbf, nullptr, kbf, sc, nullptr, nullptr, nullptr, 512, 256, 0, 0, 0);
    softmax_rows<<<CHB * 512, 256, 0, stream>>>(sc, wbf);
    mgemm<GM_AV><<<dim3(2, 4, CHB), 256, 0, stream>>>(
        wbf, nullptr, vT, nullptr, abf, nullptr, nullptr, 256, 512, 0, 0, 0);
    mgemm<GM_LG><<<dim3(1, 64), 256, 0, stream>>>(
        abf, nullptr, wtt, lg, nullptr, bt, nullptr, 48, 256, 0, b0, 0);
  }

  // ---- CRF ----
  crf_ll_k<<<BB, 64, 0, stream>>>(lg, y, seq_len, trans, out);
  crf_decode_k<<<BB, 64, 0, stream>>>(lg, seq_len, trans, out);
}

// Round 4
// 6206.820 us; speedup vs baseline: 1.3453x; 1.2204x over previous
//
#include <hip/hip_runtime.h>
#include <math.h>

typedef float f32;
typedef short short8 __attribute__((ext_vector_type(8)));
typedef float f32x4 __attribute__((ext_vector_type(4)));

#define TT 512
#define BB 64
#define DD 256
#define NN 48
#define CHB 16    // batch chunk for attention

// ===== workspace offsets (bytes). Peak ~153 MB =====
static const size_t OFF_EBF  = 0;                        // [32000][256] bf16
static const size_t OFF_PXF  = 16384000;                 // [512][64][768] bf16 (50.3MB)
static const size_t OFF_PXB  = OFF_PXF + 50331648;       // [512][64][768] bf16
static const size_t OFF_HBF_F= OFF_PXB + 50331648;       // [512][64][256] bf16
static const size_t OFF_HBF_B= OFF_HBF_F + 16777216;
static const size_t OFF_W0   = OFF_HBF_B + 16777216;     // weights block
static const size_t OFF_WXTF = OFF_W0;                   // [768][256] bf16
static const size_t OFF_WXTB = OFF_WXTF + 393216;
static const size_t OFF_WQT  = OFF_WXTB + 393216;        // [256][512] bf16
static const size_t OFF_WKT  = OFF_WQT + 262144;
static const size_t OFF_WVT  = OFF_WKT + 262144;
static const size_t OFF_WTT  = OFF_WVT + 262144;         // [48][256] bf16
static const size_t OFF_WHPF = OFF_WTT + 24576;          // packed uint2[64][768]
static const size_t OFF_WHPB = OFF_WHPF + 393216;        // end ~153.0 MB
// attn phase aliases the (dead) px arena:
static const size_t OFF_QBF = OFF_PXF;                   // [16][512][256] bf16
static const size_t OFF_KBF = OFF_QBF + 4194304;
static const size_t OFF_VBF = OFF_KBF + 4194304;
static const size_t OFF_VT  = OFF_VBF + 4194304;         // [16][256][512] bf16
static const size_t OFF_SC  = OFF_VT  + 4194304;         // [16][512][512] f32
static const size_t OFF_WBF = OFF_SC  + 16777216;        // [16][512][512] bf16
static const size_t OFF_ABF = OFF_WBF + 8388608;         // [16][512][256] bf16
static const size_t OFF_LG  = OFF_PXB;                   // [64][512][48] f32 (aliases pxb)

__device__ __forceinline__ ushort f2bf(f32 f) {
  union { f32 f; unsigned u; } v; v.f = f;
  unsigned r = v.u + 0x7fffu + ((v.u >> 16) & 1u);   // RNE
  return (ushort)(r >> 16);
}
__device__ __forceinline__ f32 bf2f(ushort u) {
  union { unsigned u; f32 f; } v; v.u = ((unsigned)u) << 16; return v.f;
}
__device__ __forceinline__ f32 bflo(unsigned u) {
  union { unsigned u; f32 f; } v; v.u = u << 16; return v.f;
}
__device__ __forceinline__ f32 bfhi(unsigned u) {
  union { unsigned u; f32 f; } v; v.u = u & 0xffff0000u; return v.f;
}

// ---------------------------------------------------------------------------
// generic transpose+convert: in f32 [P][Q] -> out bf16 [Q][P], P = 1<<PL2
template <int PL2>
__global__ __launch_bounds__(256) void tconv_k(
    const f32* __restrict__ in, ushort* __restrict__ out, int total, int Q) {
  int o = blockIdx.x * 256 + threadIdx.x;
  if (o >= total) return;
  int q = o >> PL2, p = o & ((1 << PL2) - 1);
  out[o] = f2bf(in[(size_t)p * Q + q]);
}

// embed table f32 -> bf16
__global__ __launch_bounds__(256) void conv_embed_k(
    const f32* __restrict__ in, ushort* __restrict__ out, int n4) {
  int i = blockIdx.x * 256 + threadIdx.x;
  if (i >= n4) return;
  float4 v = ((const float4*)in)[i];
  ushort4 o;
  o.x = f2bf(v.x); o.y = f2bf(v.y); o.z = f2bf(v.z); o.w = f2bf(v.w);
  ((ushort4*)out)[i] = o;
}

// pack wh [256][768] f32 -> uint2[dq=64][col=768]: d-quads per col, bf16
__global__ __launch_bounds__(256) void pack_wh_k(
    const f32* __restrict__ whf, const f32* __restrict__ whb,
    uint2* __restrict__ of, uint2* __restrict__ ob) {
  int o = blockIdx.x * 256 + threadIdx.x;     // 0..49151
  if (o >= 64 * 768) return;
  const f32* in = blockIdx.y ? whb : whf;
  uint2* out = blockIdx.y ? ob : of;
  int dq = o / 768, col = o % 768;
  unsigned a0 = f2bf(in[(4 * dq + 0) * 768 + col]);
  unsigned a1 = f2bf(in[(4 * dq + 1) * 768 + col]);
  unsigned a2 = f2bf(in[(4 * dq + 2) * 768 + col]);
  unsigned a3 = f2bf(in[(4 * dq + 3) * 768 + col]);
  out[o] = make_uint2(a0 | (a1 << 16), a2 | (a3 << 16));
}

// v transpose bf16 (per batch chunk): [16][512][256] -> [16][256][512]
__global__ __launch_bounds__(256) void tr_v_k(
    const ushort* __restrict__ in, ushort* __restrict__ out) {
  __shared__ ushort tile[32][33];
  int b = blockIdx.z;
  int s0 = blockIdx.x * 32, d0 = blockIdx.y * 32;
  int xc = threadIdx.x & 31, y0 = threadIdx.x >> 5;
  for (int yy = y0; yy < 32; yy += 8)
    tile[yy][xc] = in[((size_t)b * 512 + s0 + yy) * 256 + d0 + xc];
  __syncthreads();
  for (int yy = y0; yy < 32; yy += 8)
    out[((size_t)b * 256 + d0 + yy) * 512 + s0 + xc] = tile[xc][yy];
}

// ---------------------------------------------------------------------------
// bf16 MFMA GEMM: 128x128 block tile, BK=32, 256 thr (4 waves, 64x64 each).
enum { GM_PX = 0, GM_QKV = 1, GM_SC = 2, GM_AV = 3, GM_LG = 4 };

template <int MODE>
__global__ __launch_bounds__(256) void mgemm(
    const ushort* __restrict__ Aa, const ushort* __restrict__ Ab,
    const ushort* __restrict__ Bt,
    f32* __restrict__ Cf, ushort* __restrict__ Cb,
    const f32* __restrict__ bias, const int* __restrict__ xi,
    int Ndim, int K, int rev, int b0) {
  const int m0 = blockIdx.y * 128;
  const int n0 = blockIdx.x * 128;
  const int bz = blockIdx.z;
  const int tid = threadIdx.x;
  const int l = tid & 63, w = tid >> 6;
  const int wr = w >> 1, wc = w & 1;
  __shared__ __align__(16) short Al[128 * 40];
  __shared__ __align__(16) short Bl[128 * 40];
  f32x4 acc[4][4] = {};

  const int rowa = tid >> 1;
  const int kha = (tid & 1) * 16;
  const int rA = m0 + rowa;
  const ushort* aBase = nullptr;
  const ushort* aBase2 = nullptr;
  if constexpr (MODE == GM_PX) {
    int tg = rA >> 6, b = rA & 63;
    int ts = rev ? (511 - tg) : tg;
    aBase = Aa + (size_t)xi[b * 512 + ts] * 256;
  } else if constexpr (MODE == GM_QKV) {
    int bl = rA >> 9, t = rA & 511;
    int b = b0 + bl;
    aBase = Aa + ((size_t)(t * 64 + b)) * 256;            // fwd half
    aBase2 = Ab + ((size_t)((511 - t) * 64 + b)) * 256;   // bwd half
  } else if constexpr (MODE == GM_SC) {
    aBase = Aa + ((size_t)(bz * 512 + rA)) * 256;
  } else if constexpr (MODE == GM_AV) {
    aBase = Aa + ((size_t)(bz * 512 + rA)) * 512;
  } else {
    aBase = Aa + (size_t)rA * 256;
  }
  const int rowb = tid >> 1;
  const int khb = (tid & 1) * 16;
  int rowg = n0 + rowb;
  if constexpr (MODE == GM_SC) rowg += bz * 512;
  if constexpr (MODE == GM_AV) rowg += bz * 256;
  const ushort* bBase = Bt + (size_t)rowg * K;
  const bool bValid = (MODE != GM_LG) || (n0 + rowb < Ndim);

  for (int k0 = 0; k0 < K; k0 += 32) {
    {
      int kk = k0 + kha;
      const ushort* src;
      if constexpr (MODE == GM_QKV)
        src = (kk < 256) ? aBase + kk : aBase2 + (kk - 256);
      else
        src = aBase + kk;
      uint4 a0 = *(const uint4*)src;
      uint4 a1 = *(const uint4*)(src + 8);
      *(uint4*)&Al[rowa * 40 + kha] = a0;
      *(uint4*)&Al[rowa * 40 + kha + 8] = a1;
    }
    {
      uint4 v0 = make_uint4(0, 0, 0, 0), v1 = make_uint4(0, 0, 0, 0);
      if (bValid) {
        const ushort* src = bBase + k0 + khb;
        v0 = *(const uint4*)src;
        v1 = *(const uint4*)(src + 8);
      }
      *(uint4*)&Bl[rowb * 40 + khb] = v0;
      *(uint4*)&Bl[rowb * 40 + khb + 8] = v1;
    }
    __syncthreads();
    const int fr = l & 15, fg = l >> 4;
    short8 af[4], bfr[4];
#pragma unroll
    for (int mf = 0; mf < 4; ++mf)
      af[mf] = *(const short8*)&Al[(wr * 64 + mf * 16 + fr) * 40 + fg * 8];
#pragma unroll
    for (int nf = 0; nf < 4; ++nf)
      bfr[nf] = *(const short8*)&Bl[(wc * 64 + nf * 16 + fr) * 40 + fg * 8];
#pragma unroll
    for (int mf = 0; mf < 4; ++mf)
#pragma unroll
      for (int nf = 0; nf < 4; ++nf)
        acc[mf][nf] = __builtin_amdgcn_mfma_f32_16x16x32_bf16(
            af[mf], bfr[nf], acc[mf][nf], 0, 0, 0);
    __syncthreads();
  }

  const int fr = l & 15, fq = l >> 4;
#pragma unroll
  for (int mf = 0; mf < 4; ++mf) {
#pragma unroll
    for (int nf = 0; nf < 4; ++nf) {
      int col = n0 + wc * 64 + nf * 16 + fr;
      f32 bs = 0.f;
      if (bias && col < Ndim) bs = bias[col];
#pragma unroll
      for (int rg = 0; rg < 4; ++rg) {
        int row = m0 + wr * 64 + mf * 16 + fq * 4 + rg;
        f32 vv = acc[mf][nf][rg] + bs;
        if constexpr (MODE == GM_PX)
          Cb[(size_t)row * 768 + col] = f2bf(vv);
        else if constexpr (MODE == GM_QKV)
          Cb[(size_t)row * 256 + col] = f2bf(vv);
        else if constexpr (MODE == GM_SC)
          Cf[((size_t)bz * 512 + row) * 512 + col] = vv;
        else if constexpr (MODE == GM_AV)
          Cb[((size_t)bz * 512 + row) * 256 + col] = f2bf(vv);
        else {
          if (col < Ndim) Cf[((size_t)b0 * 512 + row) * 48 + col] = vv;
        }
      }
    }
  }
}

// ---------------------------------------------------------------------------
// persistent GRU scan: 128 blocks (dir = blk>>6, batch row = blk&63).
// Each block evolves one batch row through all 512 steps; h lives in LDS.
// No inter-block communication. Weights streamed bf16-packed from L2.
__global__ __launch_bounds__(256) void gru_scan(
    const ushort* __restrict__ pxf, const ushort* __restrict__ pxb,
    const uint2* __restrict__ whpf, const uint2* __restrict__ whpb,
    const f32* __restrict__ b_f, const f32* __restrict__ b_b,
    ushort* __restrict__ hfbf, ushort* __restrict__ hbbf) {
  const int dir = blockIdx.x >> 6;
  const int b = blockIdx.x & 63;
  const int j = threadIdx.x;                    // output column 0..255
  const ushort* px = dir ? pxb : pxf;
  const uint2* wp = dir ? whpb : whpf;
  const f32* bh = (dir ? b_b : b_f) + 768;
  ushort* hseq = dir ? hbbf : hfbf;
  __shared__ f32 hl[2][DD];
  hl[0][j] = 0.f;
  const f32 gbz = bh[j], gbr = bh[256 + j], gbh = bh[512 + j];
  __syncthreads();
  int cur = 0;
  for (int t = 0; t < TT; ++t) {
    const ushort* pxt = px + ((size_t)t * BB + b) * 768;
    const f32 xz = bf2f(pxt[j]);
    const f32 xr = bf2f(pxt[j + 256]);
    const f32 xh = bf2f(pxt[j + 512]);
    const f32* hc_ = hl[cur];
    f32 az = 0.f, ar = 0.f, ah = 0.f;
#pragma unroll 8
    for (int dq = 0; dq < 64; ++dq) {
      const uint2 uz = wp[dq * 768 + j];
      const uint2 ur = wp[dq * 768 + 256 + j];
      const uint2 uh = wp[dq * 768 + 512 + j];
      const float4 hv = *(const float4*)&hc_[4 * dq];   // LDS broadcast
      az += bflo(uz.x) * hv.x + bfhi(uz.x) * hv.y + bflo(uz.y) * hv.z + bfhi(uz.y) * hv.w;
      ar += bflo(ur.x) * hv.x + bfhi(ur.x) * hv.y + bflo(ur.y) * hv.z + bfhi(ur.y) * hv.w;
      ah += bflo(uh.x) * hv.x + bfhi(uh.x) * hv.y + bflo(uh.y) * hv.z + bfhi(uh.y) * hv.w;
    }
    const f32 z = 1.f / (1.f + expf(-(xz + az + gbz)));
    const f32 r = 1.f / (1.f + expf(-(xr + ar + gbr)));
    const f32 hcand = tanhf(xh + r * (ah + gbh));
    const f32 hold = hc_[j];
    const f32 hn = z * hold + (1.f - z) * hcand;
    hl[cur ^ 1][j] = hn;
    hseq[((size_t)t * BB + b) * DD + j] = f2bf(hn);
    __syncthreads();
    cur ^= 1;
  }
}

// ---------------------------------------------------------------------------
// row softmax over 512 elems (f32 in, bf16 out), one block per row
__global__ __launch_bounds__(256) void softmax_rows(
    const f32* __restrict__ p, ushort* __restrict__ o) {
  size_t row = blockIdx.x;
  const f32* pr = p + row * 512;
  int tid = threadIdx.x;
  f32 v0 = pr[tid], v1 = pr[tid + 256];
  f32 m = fmaxf(v0, v1);
  for (int off = 32; off; off >>= 1) m = fmaxf(m, __shfl_xor(m, off));
  __shared__ f32 red[4];
  __shared__ f32 red2[4];
  if ((tid & 63) == 0) red[tid >> 6] = m;
  __syncthreads();
  m = fmaxf(fmaxf(red[0], red[1]), fmaxf(red[2], red[3]));
  f32 e0 = expf(v0 - m), e1 = expf(v1 - m);
  f32 s = e0 + e1;
  for (int off = 32; off; off >>= 1) s += __shfl_xor(s, off);
  if ((tid & 63) == 0) red2[tid >> 6] = s;
  __syncthreads();
  s = red2[0] + red2[1] + red2[2] + red2[3];
  f32 inv = 1.f / s;
  o[row * 512 + tid] = f2bf(e0 * inv);
  o[row * 512 + tid + 256] = f2bf(e1 * inv);
}

// ---------------------------------------------------------------------------
// CRF log-likelihood, one block (1 wave) per batch element
__global__ __launch_bounds__(64) void crf_ll_k(
    const f32* __restrict__ logits, const int* __restrict__ y,
    const int* __restrict__ seq_len, const f32* __restrict__ trans,
    f32* __restrict__ out) {
  const int b = blockIdx.x, tid = threadIdx.x;
  __shared__ f32 tr[NN][NN];
  __shared__ f32 al[2][NN];
  for (int i = tid; i < NN * NN; i += 64) tr[i / NN][i % NN] = trans[i];
  const f32* em = logits + (size_t)b * TT * NN;
  const int L = seq_len[b];
  if (tid < NN) al[0][tid] = em[tid];
  __syncthreads();
  int cur = 0;
  for (int t = 1; t < TT; ++t) {
    if (t >= L) break;
    if (tid < NN) {
      f32 m = -1e30f;
      for (int i = 0; i < NN; ++i) m = fmaxf(m, al[cur][i] + tr[i][tid]);
      f32 s = 0.f;
      for (int i = 0; i < NN; ++i) s += expf(al[cur][i] + tr[i][tid] - m);
      al[cur ^ 1][tid] = m + logf(s) + em[t * NN + tid];
    }
    __syncthreads();
    cur ^= 1;
  }
  f32 us = 0.f, ts = 0.f;
  for (int t = tid; t < TT; t += 64) {
    if (t < L) {
      us += em[t * NN + y[b * TT + t]];
      if (t >= 1) ts += tr[y[b * TT + t - 1]][y[b * TT + t]];
    }
  }
  for (int off = 32; off; off >>= 1) { us += __shfl_xor(us, off); ts += __shfl_xor(ts, off); }
  if (tid == 0) {
    f32 m = -1e30f;
    for (int i = 0; i < NN; ++i) m = fmaxf(m, al[cur][i]);
    f32 s = 0.f;
    for (int i = 0; i < NN; ++i) s += expf(al[cur][i] - m);
    out[(size_t)BB * TT + b] = us + ts - (m + logf(s));
  }
}

// CRF Viterbi decode, one block (1 wave) per batch element
__global__ __launch_bounds__(64) void crf_decode_k(
    const f32* __restrict__ logits, const int* __restrict__ seq_len,
    const f32* __restrict__ trans, f32* __restrict__ out) {
  const int b = blockIdx.x, tid = threadIdx.x;
  __shared__ f32 tr[NN][NN];
  __shared__ f32 al[2][NN];
  __shared__ unsigned char bp[TT - 1][NN];
  __shared__ unsigned char pr[TT];
  for (int i = tid; i < NN * NN; i += 64) tr[i / NN][i % NN] = trans[i];
  const f32* em = logits + (size_t)b * TT * NN;
  const int L = seq_len[b];
  if (tid < NN) al[0][tid] = em[tid];
  __syncthreads();
  int cur = 0;
  for (int t = 1; t < TT; ++t) {
    if (tid < NN) {
      if (t < L) {
        f32 m = -1e30f; int arg = 0;
        for (int i = 0; i < NN; ++i) {
          f32 v = al[cur][i] + tr[i][tid];
          if (v > m) { m = v; arg = i; }
        }
        al[cur ^ 1][tid] = m + em[t * NN + tid];
        bp[t - 1][tid] = (unsigned char)arg;
      } else {
        al[cur ^ 1][tid] = al[cur][tid];
        bp[t - 1][tid] = (unsigned char)tid;
      }
    }
    __syncthreads();
    cur ^= 1;
  }
  if (tid == 0) {
    f32 m = -1e30f; int last = 0;
    for (int i = 0; i < NN; ++i)
      if (al[cur][i] > m) { m = al[cur][i]; last = i; }
    int tag = last;
    for (int t = TT - 2; t >= 0; --t) { pr[t + 1] = (unsigned char)tag; tag = bp[t][tag]; }
    pr[0] = (unsigned char)tag;
  }
  __syncthreads();
  for (int t = tid; t < TT; t += 64)
    out[(size_t)b * TT + t] = (f32)pr[t];
}

// ---------------------------------------------------------------------------
extern "C" void kernel_launch(void* const* d_in, const int* in_sizes, int n_in,
                              void* d_out, int out_size, void* d_ws, size_t ws_size,
                              hipStream_t stream) {
  const int* x       = (const int*)d_in[0];
  const int* y       = (const int*)d_in[1];
  const int* seq_len = (const int*)d_in[2];
  const f32* embed   = (const f32*)d_in[3];
  const f32* wx_f    = (const f32*)d_in[4];
  const f32* wh_f    = (const f32*)d_in[5];
  const f32* b_f     = (const f32*)d_in[6];
  const f32* wx_b    = (const f32*)d_in[7];
  const f32* wh_b    = (const f32*)d_in[8];
  const f32* b_b     = (const f32*)d_in[9];
  const f32* wq      = (const f32*)d_in[10];
  const f32* bq      = (const f32*)d_in[11];
  const f32* wk      = (const f32*)d_in[12];
  const f32* bk      = (const f32*)d_in[13];
  const f32* wv      = (const f32*)d_in[14];
  const f32* bv      = (const f32*)d_in[15];
  const f32* wt      = (const f32*)d_in[16];
  const f32* bt      = (const f32*)d_in[17];
  const f32* trans   = (const f32*)d_in[18];
  f32* out = (f32*)d_out;

  char* ws = (char*)d_ws;
  ushort* ebf  = (ushort*)(ws + OFF_EBF);
  ushort* pxfb = (ushort*)(ws + OFF_PXF);
  ushort* pxbb = (ushort*)(ws + OFF_PXB);
  ushort* hfbf = (ushort*)(ws + OFF_HBF_F);
  ushort* hbbf = (ushort*)(ws + OFF_HBF_B);
  ushort* wxtf = (ushort*)(ws + OFF_WXTF);
  ushort* wxtb = (ushort*)(ws + OFF_WXTB);
  ushort* wqt  = (ushort*)(ws + OFF_WQT);
  ushort* wkt  = (ushort*)(ws + OFF_WKT);
  ushort* wvt  = (ushort*)(ws + OFF_WVT);
  ushort* wtt  = (ushort*)(ws + OFF_WTT);
  uint2*  whpf = (uint2*)(ws + OFF_WHPF);
  uint2*  whpb = (uint2*)(ws + OFF_WHPB);
  ushort* qbf = (ushort*)(ws + OFF_QBF);
  ushort* kbf = (ushort*)(ws + OFF_KBF);
  ushort* vbf = (ushort*)(ws + OFF_VBF);
  ushort* vT  = (ushort*)(ws + OFF_VT);
  f32*    sc  = (f32*)(ws + OFF_SC);
  ushort* wbf = (ushort*)(ws + OFF_WBF);
  ushort* abf = (ushort*)(ws + OFF_ABF);
  f32*    lg  = (f32*)(ws + OFF_LG);

  // ---- setup: converts / packs ----
  conv_embed_k<<<8000, 256, 0, stream>>>(embed, ebf, 2048000);
  tconv_k<8><<<768, 256, 0, stream>>>(wx_f, wxtf, 196608, 768);
  tconv_k<8><<<768, 256, 0, stream>>>(wx_b, wxtb, 196608, 768);
  tconv_k<9><<<512, 256, 0, stream>>>(wq, wqt, 131072, 256);
  tconv_k<9><<<512, 256, 0, stream>>>(wk, wkt, 131072, 256);
  tconv_k<9><<<512, 256, 0, stream>>>(wv, wvt, 131072, 256);
  tconv_k<8><<<48, 256, 0, stream>>>(wt, wtt, 12288, 48);
  pack_wh_k<<<dim3(192, 2), 256, 0, stream>>>(wh_f, wh_b, whpf, whpb);

  // ---- px for all 512 steps (bf16 out), then ONE persistent scan ----
  mgemm<GM_PX><<<dim3(6, 256), 256, 0, stream>>>(
      ebf, nullptr, wxtf, nullptr, pxfb, b_f, x, 768, 256, 0, 0);
  mgemm<GM_PX><<<dim3(6, 256), 256, 0, stream>>>(
      ebf, nullptr, wxtb, nullptr, pxbb, b_b, x, 768, 256, 1, 0);
  gru_scan<<<128, 256, 0, stream>>>(pxfb, pxbb, whpf, whpb, b_f, b_b, hfbf, hbbf);

  // ---- attention + logits, 4 batch chunks of 16, all bf16 MFMA ----
  for (int bc = 0; bc < BB / CHB; ++bc) {
    const int b0 = bc * CHB;
    mgemm<GM_QKV><<<dim3(2, 64), 256, 0, stream>>>(
        hfbf, hbbf, wqt, nullptr, qbf, bq, nullptr, 256, 512, 0, b0);
    mgemm<GM_QKV><<<dim3(2, 64), 256, 0, stream>>>(
        hfbf, hbbf, wkt, nullptr, kbf, bk, nullptr, 256, 512, 0, b0);
    mgemm<GM_QKV><<<dim3(2, 64), 256, 0, stream>>>(
        hfbf, hbbf, wvt, nullptr, vbf, bv, nullptr, 256, 512, 0, b0);
    tr_v_k<<<dim3(16, 8, CHB), 256, 0, stream>>>(vbf, vT);
    mgemm<GM_SC><<<dim3(4, 4, CHB), 256, 0, stream>>>(
        qbf, nullptr, kbf, sc, nullptr, nullptr, nullptr, 512, 256, 0, 0);
    softmax_rows<<<CHB * 512, 256, 0, stream>>>(sc, wbf);
    mgemm<GM_AV><<<dim3(2, 4, CHB), 256, 0, stream>>>(
        wbf, nullptr, vT, nullptr, abf, nullptr, nullptr, 256, 512, 0, 0);
    mgemm<GM_LG><<<dim3(1, 64), 256, 0, stream>>>(
        abf, nullptr, wtt, lg, nullptr, bt, nullptr, 48, 256, 0, b0);
  }

  // ---- CRF ----
  crf_ll_k<<<BB, 64, 0, stream>>>(lg, y, seq_len, trans, out);
  crf_decode_k<<<BB, 64, 0, stream>>>(lg, seq_len, trans, out);
}

// Round 5
// 4946.997 us; speedup vs baseline: 1.6879x; 1.2547x over previous
//
#include <hip/hip_runtime.h>
#include <math.h>

typedef float f32;
typedef short short8 __attribute__((ext_vector_type(8)));
typedef float f32x4 __attribute__((ext_vector_type(4)));

#define TT 512
#define BB 64
#define DD 256
#define NN 48
#define CHB 16    // batch chunk for attention

// ===== workspace offsets (bytes). Peak ~146 MB =====
static const size_t OFF_EBF  = 0;                        // [32000][256] bf16
static const size_t OFF_PXF  = 16384000;                 // [512][64][768] bf16
static const size_t OFF_PXB  = OFF_PXF + 50331648;       // [512][64][768] bf16
static const size_t OFF_HBF_F= OFF_PXB + 50331648;       // [512][64][256] bf16
static const size_t OFF_HBF_B= OFF_HBF_F + 16777216;
static const size_t OFF_W0   = OFF_HBF_B + 16777216;     // weights block
static const size_t OFF_WXTF = OFF_W0;                   // [768][256] bf16
static const size_t OFF_WXTB = OFF_WXTF + 393216;
static const size_t OFF_WQT  = OFF_WXTB + 393216;        // [256][512] bf16
static const size_t OFF_WKT  = OFF_WQT + 262144;
static const size_t OFF_WVT  = OFF_WKT + 262144;
static const size_t OFF_WTT  = OFF_WVT + 262144;         // [48][256] bf16
static const size_t OFF_WHTF = OFF_WTT + 24576;          // [768][256] bf16 wh^T
static const size_t OFF_WHTB = OFF_WHTF + 393216;
static const size_t OFF_HXCH = OFF_WHTB + 393216;        // 2dir x 2buf x [64][128] uint
static const size_t OFF_SYNC = OFF_HXCH + 131072;        // barrier counters/flags
// end ~153.1 MB
// attn phase aliases the (dead) px arena:
static const size_t OFF_QBF = OFF_PXF;                   // [16][512][256] bf16
static const size_t OFF_KBF = OFF_QBF + 4194304;
static const size_t OFF_VBF = OFF_KBF + 4194304;
static const size_t OFF_VT  = OFF_VBF + 4194304;         // [16][256][512] bf16
static const size_t OFF_SC  = OFF_VT  + 4194304;         // [16][512][512] f32
static const size_t OFF_WBF = OFF_SC  + 16777216;        // [16][512][512] bf16
static const size_t OFF_ABF = OFF_WBF + 8388608;         // [16][512][256] bf16
static const size_t OFF_LG  = OFF_PXB;                   // [64][512][48] f32 (aliases pxb)

__device__ __forceinline__ ushort f2bf(f32 f) {
  union { f32 f; unsigned u; } v; v.f = f;
  unsigned r = v.u + 0x7fffu + ((v.u >> 16) & 1u);   // RNE
  return (ushort)(r >> 16);
}
__device__ __forceinline__ f32 bf2f(ushort u) {
  union { unsigned u; f32 f; } v; v.u = ((unsigned)u) << 16; return v.f;
}

// ---------------------------------------------------------------------------
__global__ __launch_bounds__(256) void zero_k(f32* __restrict__ p, int n) {
  int i = blockIdx.x * 256 + threadIdx.x;
  if (i < n) p[i] = 0.f;
}

// generic transpose+convert: in f32 [P][Q] -> out bf16 [Q][P], P = 1<<PL2
template <int PL2>
__global__ __launch_bounds__(256) void tconv_k(
    const f32* __restrict__ in, ushort* __restrict__ out, int total, int Q) {
  int o = blockIdx.x * 256 + threadIdx.x;
  if (o >= total) return;
  int q = o >> PL2, p = o & ((1 << PL2) - 1);
  out[o] = f2bf(in[(size_t)p * Q + q]);
}

// embed table f32 -> bf16
__global__ __launch_bounds__(256) void conv_embed_k(
    const f32* __restrict__ in, ushort* __restrict__ out, int n4) {
  int i = blockIdx.x * 256 + threadIdx.x;
  if (i >= n4) return;
  float4 v = ((const float4*)in)[i];
  ushort4 o;
  o.x = f2bf(v.x); o.y = f2bf(v.y); o.z = f2bf(v.z); o.w = f2bf(v.w);
  ((ushort4*)out)[i] = o;
}

// v transpose bf16 (per batch chunk): [16][512][256] -> [16][256][512]
__global__ __launch_bounds__(256) void tr_v_k(
    const ushort* __restrict__ in, ushort* __restrict__ out) {
  __shared__ ushort tile[32][33];
  int b = blockIdx.z;
  int s0 = blockIdx.x * 32, d0 = blockIdx.y * 32;
  int xc = threadIdx.x & 31, y0 = threadIdx.x >> 5;
  for (int yy = y0; yy < 32; yy += 8)
    tile[yy][xc] = in[((size_t)b * 512 + s0 + yy) * 256 + d0 + xc];
  __syncthreads();
  for (int yy = y0; yy < 32; yy += 8)
    out[((size_t)b * 256 + d0 + yy) * 512 + s0 + xc] = tile[xc][yy];
}

// ---------------------------------------------------------------------------
// bf16 MFMA GEMM: 128x128 block tile, BK=32, 256 thr (4 waves, 64x64 each).
enum { GM_PX = 0, GM_QKV = 1, GM_SC = 2, GM_AV = 3, GM_LG = 4 };

template <int MODE>
__global__ __launch_bounds__(256) void mgemm(
    const ushort* __restrict__ Aa, const ushort* __restrict__ Ab,
    const ushort* __restrict__ Bt,
    f32* __restrict__ Cf, ushort* __restrict__ Cb,
    const f32* __restrict__ bias, const int* __restrict__ xi,
    int Ndim, int K, int rev, int b0) {
  const int m0 = blockIdx.y * 128;
  const int n0 = blockIdx.x * 128;
  const int bz = blockIdx.z;
  const int tid = threadIdx.x;
  const int l = tid & 63, w = tid >> 6;
  const int wr = w >> 1, wc = w & 1;
  __shared__ __align__(16) short Al[128 * 40];
  __shared__ __align__(16) short Bl[128 * 40];
  f32x4 acc[4][4] = {};

  const int rowa = tid >> 1;
  const int kha = (tid & 1) * 16;
  const int rA = m0 + rowa;
  const ushort* aBase = nullptr;
  const ushort* aBase2 = nullptr;
  if constexpr (MODE == GM_PX) {
    int tg = rA >> 6, b = rA & 63;
    int ts = rev ? (511 - tg) : tg;
    aBase = Aa + (size_t)xi[b * 512 + ts] * 256;
  } else if constexpr (MODE == GM_QKV) {
    int bl = rA >> 9, t = rA & 511;
    int b = b0 + bl;
    aBase = Aa + ((size_t)(t * 64 + b)) * 256;            // fwd half
    aBase2 = Ab + ((size_t)((511 - t) * 64 + b)) * 256;   // bwd half
  } else if constexpr (MODE == GM_SC) {
    aBase = Aa + ((size_t)(bz * 512 + rA)) * 256;
  } else if constexpr (MODE == GM_AV) {
    aBase = Aa + ((size_t)(bz * 512 + rA)) * 512;
  } else {
    aBase = Aa + (size_t)rA * 256;
  }
  const int rowb = tid >> 1;
  const int khb = (tid & 1) * 16;
  int rowg = n0 + rowb;
  if constexpr (MODE == GM_SC) rowg += bz * 512;
  if constexpr (MODE == GM_AV) rowg += bz * 256;
  const ushort* bBase = Bt + (size_t)rowg * K;
  const bool bValid = (MODE != GM_LG) || (n0 + rowb < Ndim);

  for (int k0 = 0; k0 < K; k0 += 32) {
    {
      int kk = k0 + kha;
      const ushort* src;
      if constexpr (MODE == GM_QKV)
        src = (kk < 256) ? aBase + kk : aBase2 + (kk - 256);
      else
        src = aBase + kk;
      uint4 a0 = *(const uint4*)src;
      uint4 a1 = *(const uint4*)(src + 8);
      *(uint4*)&Al[rowa * 40 + kha] = a0;
      *(uint4*)&Al[rowa * 40 + kha + 8] = a1;
    }
    {
      uint4 v0 = make_uint4(0, 0, 0, 0), v1 = make_uint4(0, 0, 0, 0);
      if (bValid) {
        const ushort* src = bBase + k0 + khb;
        v0 = *(const uint4*)src;
        v1 = *(const uint4*)(src + 8);
      }
      *(uint4*)&Bl[rowb * 40 + khb] = v0;
      *(uint4*)&Bl[rowb * 40 + khb + 8] = v1;
    }
    __syncthreads();
    const int fr = l & 15, fg = l >> 4;
    short8 af[4], bfr[4];
#pragma unroll
    for (int mf = 0; mf < 4; ++mf)
      af[mf] = *(const short8*)&Al[(wr * 64 + mf * 16 + fr) * 40 + fg * 8];
#pragma unroll
    for (int nf = 0; nf < 4; ++nf)
      bfr[nf] = *(const short8*)&Bl[(wc * 64 + nf * 16 + fr) * 40 + fg * 8];
#pragma unroll
    for (int mf = 0; mf < 4; ++mf)
#pragma unroll
      for (int nf = 0; nf < 4; ++nf)
        acc[mf][nf] = __builtin_amdgcn_mfma_f32_16x16x32_bf16(
            af[mf], bfr[nf], acc[mf][nf], 0, 0, 0);
    __syncthreads();
  }

  const int fr = l & 15, fq = l >> 4;
#pragma unroll
  for (int mf = 0; mf < 4; ++mf) {
#pragma unroll
    for (int nf = 0; nf < 4; ++nf) {
      int col = n0 + wc * 64 + nf * 16 + fr;
      f32 bs = 0.f;
      if (bias && col < Ndim) bs = bias[col];
#pragma unroll
      for (int rg = 0; rg < 4; ++rg) {
        int row = m0 + wr * 64 + mf * 16 + fq * 4 + rg;
        f32 vv = acc[mf][nf][rg] + bs;
        if constexpr (MODE == GM_PX)
          Cb[(size_t)row * 768 + col] = f2bf(vv);
        else if constexpr (MODE == GM_QKV)
          Cb[(size_t)row * 256 + col] = f2bf(vv);
        else if constexpr (MODE == GM_SC)
          Cf[((size_t)bz * 512 + row) * 512 + col] = vv;
        else if constexpr (MODE == GM_AV)
          Cb[((size_t)bz * 512 + row) * 256 + col] = f2bf(vv);
        else {
          if (col < Ndim) Cf[((size_t)b0 * 512 + row) * 48 + col] = vv;
        }
      }
    }
  }
}

// ---------------------------------------------------------------------------
// MFMA GRU scan with per-step inter-WG barrier.
// Grid = 16 WGs: dir = blk>>3, wg = blk&7. WG owns 32 h-cols (96 gate-cols),
// weight slab resident in LDS for all 512 steps. h exchanged via agent-scope
// (coherent) atomics in a ping-pong buffer; f32 carry kept in registers.
__global__ __launch_bounds__(256) void gru_scan2(
    const ushort* __restrict__ pxf, const ushort* __restrict__ pxb,
    const ushort* __restrict__ whtf, const ushort* __restrict__ whtb,
    const f32* __restrict__ b_f, const f32* __restrict__ b_b,
    uint* hxch, uint* syncv,
    ushort* __restrict__ hfbf, ushort* __restrict__ hbbf) {
  const int dir = blockIdx.x >> 3;
  const int wg  = blockIdx.x & 7;
  const int wgbase = wg * 32;
  const int tid = threadIdx.x;
  const int l = tid & 63, wv = tid >> 6;
  const int fr = l & 15, fq = (l >> 4) & 3;
  const ushort* px  = dir ? pxb : pxf;
  const ushort* wht = dir ? whtb : whtf;
  const f32* bh = (dir ? b_b : b_f) + 768;
  ushort* hseq = dir ? hbbf : hfbf;
  uint* hbuf = hxch + dir * 16384;          // 2 bufs x 8192 uint
  uint* cnt  = syncv + dir * 32;
  uint* flag = syncv + 64 + dir * 32;

  __shared__ __align__(16) short lds[40960];  // H [64][256] @0; W [96][256] @16384
  short* ldsH = lds;
  short* ldsW = lds + 16384;

  // ---- stage W slab (96 gate-cols x 256 k), XOR-swizzled, once ----
  for (int i = tid; i < 3072; i += 256) {
    int rr = i >> 5, ch = i & 31;
    int gc = (rr < 32) ? (wgbase + rr)
           : (rr < 64) ? (256 + wgbase + rr - 32)
                       : (512 + wgbase + rr - 64);
    uint4 v = *(const uint4*)&wht[(size_t)gc * 256 + ch * 8];
    *(uint4*)((char*)ldsW + rr * 512 + ((ch * 16) ^ ((rr & 7) << 4))) = v;
  }
  f32 bhz[2], bhr[2], bhh[2];
#pragma unroll
  for (int ct = 0; ct < 2; ++ct) {
    int colg = wgbase + ct * 16 + fr;
    bhz[ct] = bh[colg]; bhr[ct] = bh[256 + colg]; bhh[ct] = bh[512 + colg];
  }
  f32 hold[8];
#pragma unroll
  for (int i = 0; i < 8; ++i) hold[i] = 0.f;
  __syncthreads();

#pragma unroll 1
  for (int t = 0; t < TT; ++t) {
    // px prefetch (issued early; consumed after MFMA)
    ushort pxv[24];
    {
      const ushort* pxt = px + (size_t)t * 64 * 768;
#pragma unroll
      for (int ct = 0; ct < 2; ++ct)
#pragma unroll
        for (int rg = 0; rg < 4; ++rg) {
          int row = wv * 16 + fq * 4 + rg;
          int colg = wgbase + ct * 16 + fr;
          const ushort* p = pxt + row * 768 + colg;
          pxv[(ct * 4 + rg) * 3 + 0] = p[0];
          pxv[(ct * 4 + rg) * 3 + 1] = p[256];
          pxv[(ct * 4 + rg) * 3 + 2] = p[512];
        }
    }
    // coherent h load -> swizzled LDS
    uint* hsrc = hbuf + (t & 1) * 8192;
    uint* hdst = hbuf + ((t + 1) & 1) * 8192;
    uint hv[32];
#pragma unroll
    for (int i = 0; i < 32; ++i)
      hv[i] = __hip_atomic_load(&hsrc[tid + i * 256], __ATOMIC_RELAXED,
                                __HIP_MEMORY_SCOPE_AGENT);
#pragma unroll
    for (int i = 0; i < 32; ++i) {
      int g = tid + i * 256;
      int row = g >> 7, cp = g & 127;
      *(uint*)((char*)ldsH + row * 512 + ((cp * 4) ^ ((row & 7) << 4))) = hv[i];
    }
    __syncthreads();
    // MFMA matvec: C[64 rows x 96 gate-cols]
    f32x4 acc[6] = {};
    const int arow = wv * 16 + fr;
#pragma unroll
    for (int kt = 0; kt < 8; ++kt) {
      short8 a = *(const short8*)((char*)ldsH + arow * 512 +
                                  ((kt * 64 + fq * 16) ^ ((arow & 7) << 4)));
#pragma unroll
      for (int n = 0; n < 6; ++n) {
        int brow = n * 16 + fr;
        short8 b = *(const short8*)((char*)ldsW + brow * 512 +
                                    ((kt * 64 + fq * 16) ^ ((brow & 7) << 4)));
        acc[n] = __builtin_amdgcn_mfma_f32_16x16x32_bf16(a, b, acc[n], 0, 0, 0);
      }
    }
    // gates + publish
#pragma unroll
    for (int ct = 0; ct < 2; ++ct) {
#pragma unroll
      for (int rg = 0; rg < 4; ++rg) {
        int idx = ct * 4 + rg;
        int row = wv * 16 + fq * 4 + rg;
        int colg = wgbase + ct * 16 + fr;
        f32 xz = bf2f(pxv[idx * 3 + 0]);
        f32 xr = bf2f(pxv[idx * 3 + 1]);
        f32 xh = bf2f(pxv[idx * 3 + 2]);
        f32 zv = 1.f / (1.f + __expf(-(xz + acc[ct][rg] + bhz[ct])));
        f32 rv = 1.f / (1.f + __expf(-(xr + acc[2 + ct][rg] + bhr[ct])));
        f32 hc = tanhf(xh + rv * (acc[4 + ct][rg] + bhh[ct]));
        f32 hn = zv * hold[idx] + (1.f - zv) * hc;
        hold[idx] = hn;
        ushort mybf = f2bf(hn);
        int other = __shfl_xor((int)mybf, 1);
        uint packed = (l & 1) ? (((uint)(ushort)other) | ((uint)mybf << 16))
                              : (((uint)mybf) | (((uint)(ushort)other) << 16));
        int cp = (colg & ~1) >> 1;
        if ((l & 1) == 0)
          __hip_atomic_store(&hdst[row * 128 + cp], packed, __ATOMIC_RELAXED,
                             __HIP_MEMORY_SCOPE_AGENT);
        else
          *(uint*)&hseq[((size_t)t * 64 + row) * 256 + (colg & ~1)] = packed;
      }
    }
    // inter-WG barrier (per direction, 8 WGs, all co-resident)
    __syncthreads();
    if (tid == 0) {
      uint old = __hip_atomic_fetch_add(cnt, 1u, __ATOMIC_ACQ_REL,
                                        __HIP_MEMORY_SCOPE_AGENT);
      if (old == (uint)(t * 8 + 7)) {
        __hip_atomic_store(flag, (uint)(t + 1), __ATOMIC_RELEASE,
                           __HIP_MEMORY_SCOPE_AGENT);
      } else {
        while (__hip_atomic_load(flag, __ATOMIC_ACQUIRE,
                                 __HIP_MEMORY_SCOPE_AGENT) < (uint)(t + 1)) {}
      }
    }
    __syncthreads();
  }
}

// ---------------------------------------------------------------------------
// row softmax over 512 elems (f32 in, bf16 out), one block per row
__global__ __launch_bounds__(256) void softmax_rows(
    const f32* __restrict__ p, ushort* __restrict__ o) {
  size_t row = blockIdx.x;
  const f32* pr = p + row * 512;
  int tid = threadIdx.x;
  f32 v0 = pr[tid], v1 = pr[tid + 256];
  f32 m = fmaxf(v0, v1);
  for (int off = 32; off; off >>= 1) m = fmaxf(m, __shfl_xor(m, off));
  __shared__ f32 red[4];
  __shared__ f32 red2[4];
  if ((tid & 63) == 0) red[tid >> 6] = m;
  __syncthreads();
  m = fmaxf(fmaxf(red[0], red[1]), fmaxf(red[2], red[3]));
  f32 e0 = expf(v0 - m), e1 = expf(v1 - m);
  f32 s = e0 + e1;
  for (int off = 32; off; off >>= 1) s += __shfl_xor(s, off);
  if ((tid & 63) == 0) red2[tid >> 6] = s;
  __syncthreads();
  s = red2[0] + red2[1] + red2[2] + red2[3];
  f32 inv = 1.f / s;
  o[row * 512 + tid] = f2bf(e0 * inv);
  o[row * 512 + tid + 256] = f2bf(e1 * inv);
}

// ---------------------------------------------------------------------------
// CRF log-likelihood, one block (1 wave) per batch element
__global__ __launch_bounds__(64) void crf_ll_k(
    const f32* __restrict__ logits, const int* __restrict__ y,
    const int* __restrict__ seq_len, const f32* __restrict__ trans,
    f32* __restrict__ out) {
  const int b = blockIdx.x, tid = threadIdx.x;
  __shared__ f32 tr[NN][NN];
  __shared__ f32 al[2][NN];
  for (int i = tid; i < NN * NN; i += 64) tr[i / NN][i % NN] = trans[i];
  const f32* em = logits + (size_t)b * TT * NN;
  const int L = seq_len[b];
  if (tid < NN) al[0][tid] = em[tid];
  __syncthreads();
  int cur = 0;
  for (int t = 1; t < TT; ++t) {
    if (t >= L) break;
    if (tid < NN) {
      f32 m = -1e30f;
      for (int i = 0; i < NN; ++i) m = fmaxf(m, al[cur][i] + tr[i][tid]);
      f32 s = 0.f;
      for (int i = 0; i < NN; ++i) s += expf(al[cur][i] + tr[i][tid] - m);
      al[cur ^ 1][tid] = m + logf(s) + em[t * NN + tid];
    }
    __syncthreads();
    cur ^= 1;
  }
  f32 us = 0.f, ts = 0.f;
  for (int t = tid; t < TT; t += 64) {
    if (t < L) {
      us += em[t * NN + y[b * TT + t]];
      if (t >= 1) ts += tr[y[b * TT + t - 1]][y[b * TT + t]];
    }
  }
  for (int off = 32; off; off >>= 1) { us += __shfl_xor(us, off); ts += __shfl_xor(ts, off); }
  if (tid == 0) {
    f32 m = -1e30f;
    for (int i = 0; i < NN; ++i) m = fmaxf(m, al[cur][i]);
    f32 s = 0.f;
    for (int i = 0; i < NN; ++i) s += expf(al[cur][i] - m);
    out[(size_t)BB * TT + b] = us + ts - (m + logf(s));
  }
}

// CRF Viterbi decode, one block (1 wave) per batch element
__global__ __launch_bounds__(64) void crf_decode_k(
    const f32* __restrict__ logits, const int* __restrict__ seq_len,
    const f32* __restrict__ trans, f32* __restrict__ out) {
  const int b = blockIdx.x, tid = threadIdx.x;
  __shared__ f32 tr[NN][NN];
  __shared__ f32 al[2][NN];
  __shared__ unsigned char bp[TT - 1][NN];
  __shared__ unsigned char pr[TT];
  for (int i = tid; i < NN * NN; i += 64) tr[i / NN][i % NN] = trans[i];
  const f32* em = logits + (size_t)b * TT * NN;
  const int L = seq_len[b];
  if (tid < NN) al[0][tid] = em[tid];
  __syncthreads();
  int cur = 0;
  for (int t = 1; t < TT; ++t) {
    if (tid < NN) {
      if (t < L) {
        f32 m = -1e30f; int arg = 0;
        for (int i = 0; i < NN; ++i) {
          f32 v = al[cur][i] + tr[i][tid];
          if (v > m) { m = v; arg = i; }
        }
        al[cur ^ 1][tid] = m + em[t * NN + tid];
        bp[t - 1][tid] = (unsigned char)arg;
      } else {
        al[cur ^ 1][tid] = al[cur][tid];
        bp[t - 1][tid] = (unsigned char)tid;
      }
    }
    __syncthreads();
    cur ^= 1;
  }
  if (tid == 0) {
    f32 m = -1e30f; int last = 0;
    for (int i = 0; i < NN; ++i)
      if (al[cur][i] > m) { m = al[cur][i]; last = i; }
    int tag = last;
    for (int t = TT - 2; t >= 0; --t) { pr[t + 1] = (unsigned char)tag; tag = bp[t][tag]; }
    pr[0] = (unsigned char)tag;
  }
  __syncthreads();
  for (int t = tid; t < TT; t += 64)
    out[(size_t)b * TT + t] = (f32)pr[t];
}

// ---------------------------------------------------------------------------
extern "C" void kernel_launch(void* const* d_in, const int* in_sizes, int n_in,
                              void* d_out, int out_size, void* d_ws, size_t ws_size,
                              hipStream_t stream) {
  const int* x       = (const int*)d_in[0];
  const int* y       = (const int*)d_in[1];
  const int* seq_len = (const int*)d_in[2];
  const f32* embed   = (const f32*)d_in[3];
  const f32* wx_f    = (const f32*)d_in[4];
  const f32* wh_f    = (const f32*)d_in[5];
  const f32* b_f     = (const f32*)d_in[6];
  const f32* wx_b    = (const f32*)d_in[7];
  const f32* wh_b    = (const f32*)d_in[8];
  const f32* b_b     = (const f32*)d_in[9];
  const f32* wq      = (const f32*)d_in[10];
  const f32* bq      = (const f32*)d_in[11];
  const f32* wk      = (const f32*)d_in[12];
  const f32* bk      = (const f32*)d_in[13];
  const f32* wv      = (const f32*)d_in[14];
  const f32* bv      = (const f32*)d_in[15];
  const f32* wt      = (const f32*)d_in[16];
  const f32* bt      = (const f32*)d_in[17];
  const f32* trans   = (const f32*)d_in[18];
  f32* out = (f32*)d_out;

  char* ws = (char*)d_ws;
  ushort* ebf  = (ushort*)(ws + OFF_EBF);
  ushort* pxfb = (ushort*)(ws + OFF_PXF);
  ushort* pxbb = (ushort*)(ws + OFF_PXB);
  ushort* hfbf = (ushort*)(ws + OFF_HBF_F);
  ushort* hbbf = (ushort*)(ws + OFF_HBF_B);
  ushort* wxtf = (ushort*)(ws + OFF_WXTF);
  ushort* wxtb = (ushort*)(ws + OFF_WXTB);
  ushort* wqt  = (ushort*)(ws + OFF_WQT);
  ushort* wkt  = (ushort*)(ws + OFF_WKT);
  ushort* wvt  = (ushort*)(ws + OFF_WVT);
  ushort* wtt  = (ushort*)(ws + OFF_WTT);
  ushort* whtf = (ushort*)(ws + OFF_WHTF);
  ushort* whtb = (ushort*)(ws + OFF_WHTB);
  uint*   hxch = (uint*)(ws + OFF_HXCH);
  uint*   syncv= (uint*)(ws + OFF_SYNC);
  ushort* qbf = (ushort*)(ws + OFF_QBF);
  ushort* kbf = (ushort*)(ws + OFF_KBF);
  ushort* vbf = (ushort*)(ws + OFF_VBF);
  ushort* vT  = (ushort*)(ws + OFF_VT);
  f32*    sc  = (f32*)(ws + OFF_SC);
  ushort* wbf = (ushort*)(ws + OFF_WBF);
  ushort* abf = (ushort*)(ws + OFF_ABF);
  f32*    lg  = (f32*)(ws + OFF_LG);

  // ---- setup: converts + zero of h-exchange/barrier state ----
  conv_embed_k<<<8000, 256, 0, stream>>>(embed, ebf, 2048000);
  tconv_k<8><<<768, 256, 0, stream>>>(wx_f, wxtf, 196608, 768);
  tconv_k<8><<<768, 256, 0, stream>>>(wx_b, wxtb, 196608, 768);
  tconv_k<8><<<768, 256, 0, stream>>>(wh_f, whtf, 196608, 768);
  tconv_k<8><<<768, 256, 0, stream>>>(wh_b, whtb, 196608, 768);
  tconv_k<9><<<512, 256, 0, stream>>>(wq, wqt, 131072, 256);
  tconv_k<9><<<512, 256, 0, stream>>>(wk, wkt, 131072, 256);
  tconv_k<9><<<512, 256, 0, stream>>>(wv, wvt, 131072, 256);
  tconv_k<8><<<48, 256, 0, stream>>>(wt, wtt, 12288, 48);
  zero_k<<<130, 256, 0, stream>>>((f32*)(ws + OFF_HXCH), 33024);

  // ---- px for all 512 steps, then ONE barrier-synced MFMA scan ----
  mgemm<GM_PX><<<dim3(6, 256), 256, 0, stream>>>(
      ebf, nullptr, wxtf, nullptr, pxfb, b_f, x, 768, 256, 0, 0);
  mgemm<GM_PX><<<dim3(6, 256), 256, 0, stream>>>(
      ebf, nullptr, wxtb, nullptr, pxbb, b_b, x, 768, 256, 1, 0);
  gru_scan2<<<16, 256, 0, stream>>>(pxfb, pxbb, whtf, whtb, b_f, b_b,
                                    hxch, syncv, hfbf, hbbf);

  // ---- attention + logits, 4 batch chunks of 16, all bf16 MFMA ----
  for (int bc = 0; bc < BB / CHB; ++bc) {
    const int b0 = bc * CHB;
    mgemm<GM_QKV><<<dim3(2, 64), 256, 0, stream>>>(
        hfbf, hbbf, wqt, nullptr, qbf, bq, nullptr, 256, 512, 0, b0);
    mgemm<GM_QKV><<<dim3(2, 64), 256, 0, stream>>>(
        hfbf, hbbf, wkt, nullptr, kbf, bk, nullptr, 256, 512, 0, b0);
    mgemm<GM_QKV><<<dim3(2, 64), 256, 0, stream>>>(
        hfbf, hbbf, wvt, nullptr, vbf, bv, nullptr, 256, 512, 0, b0);
    tr_v_k<<<dim3(16, 8, CHB), 256, 0, stream>>>(vbf, vT);
    mgemm<GM_SC><<<dim3(4, 4, CHB), 256, 0, stream>>>(
        qbf, nullptr, kbf, sc, nullptr, nullptr, nullptr, 512, 256, 0, 0);
    softmax_rows<<<CHB * 512, 256, 0, stream>>>(sc, wbf);
    mgemm<GM_AV><<<dim3(2, 4, CHB), 256, 0, stream>>>(
        wbf, nullptr, vT, nullptr, abf, nullptr, nullptr, 256, 512, 0, 0);
    mgemm<GM_LG><<<dim3(1, 64), 256, 0, stream>>>(
        abf, nullptr, wtt, lg, nullptr, bt, nullptr, 48, 256, 0, b0);
  }

  // ---- CRF ----
  crf_ll_k<<<BB, 64, 0, stream>>>(lg, y, seq_len, trans, out);
  crf_decode_k<<<BB, 64, 0, stream>>>(lg, seq_len, trans, out);
}